// Round 1
// baseline (5509.609 us; speedup 1.0000x reference)
//
#include <hip/hip_runtime.h>
#include <hip/hip_bf16.h>
#include <math.h>

#define B_ 32
#define S_ 100
#define D_ 1024
#define H_ 16
#define L_ 2
#define V_ 32000
#define DF_ 4096
#define HD_ 64

// ------------------------------------------------------------------
// g = mean(|dec_w|) in float64 (order-insensitive to ~1e-13 relative,
// so ternary rounding decisions are stable and match a float64 np ref)
// ------------------------------------------------------------------
__global__ void absmean_kernel(const float* __restrict__ w, double* __restrict__ out) {
  const long long n = (long long)V_ * D_;
  double s = 0.0;
  long long stride = (long long)gridDim.x * blockDim.x;
  for (long long i = (long long)blockIdx.x * blockDim.x + threadIdx.x; i < n; i += stride)
    s += (double)fabsf(w[i]);
#pragma unroll
  for (int off = 32; off > 0; off >>= 1) s += __shfl_down(s, off);
  __shared__ double sm[4];
  int lane = threadIdx.x & 63, wv = threadIdx.x >> 6;
  if (lane == 0) sm[wv] = s;
  __syncthreads();
  if (threadIdx.x == 0) atomicAdd(out, sm[0] + sm[1] + sm[2] + sm[3]);
}

// packed effective ternary weight: {q==0:+1, q==+1:-1, q==-1:0}
__global__ void quantize_kernel(const float* __restrict__ w, const double* __restrict__ gsum,
                                signed char* __restrict__ q) {
  const long long n = (long long)V_ * D_;
  double g = (*gsum) / (double)n + 1e-6;  // g + EPS_Q
  long long stride = (long long)gridDim.x * blockDim.x;
  for (long long i = (long long)blockIdx.x * blockDim.x + threadIdx.x; i < n; i += stride) {
    double z = (double)w[i] / g;
    double r = rint(z);                    // half-to-even, matches np.round
    r = fmin(1.0, fmax(-1.0, r));
    q[i] = (r == 0.0) ? (signed char)1 : ((r == 1.0) ? (signed char)-1 : (signed char)0);
  }
}

// ------------------------------------------------------------------
// h[b,s,:] = emb[x[b,s],:] + pos[s,:]
// ------------------------------------------------------------------
__global__ __launch_bounds__(256) void embed_kernel(const int* __restrict__ x,
    const float* __restrict__ emb, const float* __restrict__ pos, float* __restrict__ h) {
  int row = blockIdx.x;        // b*S + s
  int s = row % S_;
  int tok = x[row];
  size_t eb = (size_t)tok * D_, pb = (size_t)s * D_, hb = (size_t)row * D_;
#pragma unroll
  for (int i = 0; i < 4; ++i) {
    int d = threadIdx.x + i * 256;
    h[hb + d] = emb[eb + d] + pos[pb + d];
  }
}

// ------------------------------------------------------------------
// C[M,N] = act(A[M,K] * B[N,K]^T + bias[N]); fp32 tiled 64x64x16.
// All launch dims divide exactly (M=3200, N%64==0, K%16==0).
// ------------------------------------------------------------------
__device__ __forceinline__ float gelu_exact(float v) {
  return 0.5f * v * (1.0f + erff(v * 0.70710678118654752f));
}

template <int ACT, typename BT>
__global__ __launch_bounds__(256) void gemm_nt(const float* __restrict__ A,
    const BT* __restrict__ Bm, const float* __restrict__ bias, float* __restrict__ C,
    int M, int N, int K, int lda, int ldb, int ldc) {
  __shared__ float As[16][68];   // [k][m], row stride 272B keeps float4 alignment
  __shared__ float Bs[16][68];   // [k][n]
  int tid = threadIdx.x;
  int tx = tid & 15, ty = tid >> 4;
  int row0 = blockIdx.y * 64, col0 = blockIdx.x * 64;
  float acc[4][4] = {};
  for (int k0 = 0; k0 < K; k0 += 16) {
#pragma unroll
    for (int r = 0; r < 4; ++r) {
      int mn = ty + r * 16;
      As[tx][mn] = A[(size_t)(row0 + mn) * lda + k0 + tx];
      Bs[tx][mn] = (float)Bm[(size_t)(col0 + mn) * ldb + k0 + tx];
    }
    __syncthreads();
#pragma unroll
    for (int kk = 0; kk < 16; ++kk) {
      float4 a4 = *(const float4*)&As[kk][ty * 4];
      float4 b4 = *(const float4*)&Bs[kk][tx * 4];
      float a[4] = {a4.x, a4.y, a4.z, a4.w};
      float b[4] = {b4.x, b4.y, b4.z, b4.w};
#pragma unroll
      for (int i = 0; i < 4; ++i)
#pragma unroll
        for (int j = 0; j < 4; ++j) acc[i][j] += a[i] * b[j];
    }
    __syncthreads();
  }
#pragma unroll
  for (int i = 0; i < 4; ++i) {
    int m = row0 + ty * 4 + i;
    int n = col0 + tx * 4;
    float4 o;
    float* ov = &o.x;
#pragma unroll
    for (int j = 0; j < 4; ++j) {
      float v = acc[i][j] + bias[n + j];
      if (ACT == 1) v = gelu_exact(v);
      ov[j] = v;
    }
    *(float4*)&C[(size_t)m * ldc + n] = o;
  }
}

// ------------------------------------------------------------------
// Fused attention per (b,h): scores -> softmax -> ctx. S=100, hd=64.
// K/V staged in LDS in two 50-row tiles; scores matrix in LDS (40KB).
// Total LDS 52.8KB < 64KB. One thread per q-row (100 of 128 active).
// ------------------------------------------------------------------
__global__ __launch_bounds__(128) void attn_kernel(const float* __restrict__ qkv,
                                                   float* __restrict__ ctx) {
  __shared__ float KV[50][64];
  __shared__ float Sc[100][100];
  int bh = blockIdx.x;            // b*H + h
  int b = bh >> 4, hh = bh & 15;
  int tid = threadIdx.x;
  size_t base = (size_t)b * S_ * (3 * D_);
  int hcol = hh * HD_;
  int r = tid;

  float qa[64];
  if (r < 100) {
    const float* qp = qkv + base + (size_t)r * (3 * D_) + hcol;
#pragma unroll
    for (int d = 0; d < 64; ++d) qa[d] = qp[d];
  }
  // ---- scores = q.K^T / 8 ----
  for (int t = 0; t < 2; ++t) {
    __syncthreads();
    for (int idx = tid; idx < 3200; idx += 128) {
      int j = idx >> 6, d = idx & 63;
      KV[j][d] = qkv[base + (size_t)(t * 50 + j) * (3 * D_) + D_ + hcol + d];
    }
    __syncthreads();
    if (r < 100) {
      for (int j = 0; j < 50; ++j) {
        float s = 0.f;
#pragma unroll
        for (int d0 = 0; d0 < 16; ++d0) {
          float4 kv = *(const float4*)&KV[j][d0 * 4];
          s += qa[d0 * 4 + 0] * kv.x + qa[d0 * 4 + 1] * kv.y +
               qa[d0 * 4 + 2] * kv.z + qa[d0 * 4 + 3] * kv.w;
        }
        Sc[r][t * 50 + j] = s * 0.125f;
      }
    }
  }
  // ---- softmax along own row (no cross-thread deps) ----
  float inv_sum = 0.f;
  if (r < 100) {
    float mx = -1e30f;
    for (int j = 0; j < 100; ++j) mx = fmaxf(mx, Sc[r][j]);
    float sum = 0.f;
    for (int j = 0; j < 100; ++j) {
      float e = expf(Sc[r][j] - mx);
      Sc[r][j] = e;
      sum += e;
    }
    inv_sum = 1.0f / sum;
  }
  // ---- ctx = P.V ----
  float ca[64];
#pragma unroll
  for (int d = 0; d < 64; ++d) ca[d] = 0.f;
  for (int t = 0; t < 2; ++t) {
    __syncthreads();
    for (int idx = tid; idx < 3200; idx += 128) {
      int j = idx >> 6, d = idx & 63;
      KV[j][d] = qkv[base + (size_t)(t * 50 + j) * (3 * D_) + 2 * D_ + hcol + d];
    }
    __syncthreads();
    if (r < 100) {
      for (int j = 0; j < 50; ++j) {
        float p = Sc[r][t * 50 + j];
#pragma unroll
        for (int d0 = 0; d0 < 16; ++d0) {
          float4 kv = *(const float4*)&KV[j][d0 * 4];
          ca[d0 * 4 + 0] += p * kv.x;
          ca[d0 * 4 + 1] += p * kv.y;
          ca[d0 * 4 + 2] += p * kv.z;
          ca[d0 * 4 + 3] += p * kv.w;
        }
      }
    }
  }
  if (r < 100) {
    float* cp = ctx + ((size_t)b * S_ + r) * D_ + hcol;
#pragma unroll
    for (int d = 0; d < 64; ++d) cp[d] = ca[d] * inv_sum;
  }
}

// ------------------------------------------------------------------
// h = LN(h + res) * scale + bias   (one block per row, D=1024)
// ------------------------------------------------------------------
__device__ float block_sum_1024(float v) {
#pragma unroll
  for (int off = 32; off > 0; off >>= 1) v += __shfl_down(v, off);
  __shared__ float sm[4];
  __syncthreads();
  int lane = threadIdx.x & 63, wv = threadIdx.x >> 6;
  if (lane == 0) sm[wv] = v;
  __syncthreads();
  return sm[0] + sm[1] + sm[2] + sm[3];
}

__global__ __launch_bounds__(256) void add_ln_kernel(float* __restrict__ h,
    const float* __restrict__ res, const float* __restrict__ scale,
    const float* __restrict__ bias) {
  size_t base = (size_t)blockIdx.x * D_;
  int tid = threadIdx.x;
  float x[4];
  float s = 0.f;
#pragma unroll
  for (int i = 0; i < 4; ++i) {
    x[i] = h[base + tid + i * 256] + res[base + tid + i * 256];
    s += x[i];
  }
  float mu = block_sum_1024(s) * (1.0f / 1024.0f);
  float v = 0.f;
#pragma unroll
  for (int i = 0; i < 4; ++i) {
    float d = x[i] - mu;
    v += d * d;
  }
  float var = block_sum_1024(v) * (1.0f / 1024.0f);
  float rs = rsqrtf(var + 1e-5f);
#pragma unroll
  for (int i = 0; i < 4; ++i) {
    int d = tid + i * 256;
    h[base + d] = (x[i] - mu) * rs * scale[d] + bias[d];
  }
}

// ------------------------------------------------------------------
extern "C" void kernel_launch(void* const* d_in, const int* in_sizes, int n_in,
                              void* d_out, int out_size, void* d_ws, size_t ws_size,
                              hipStream_t stream) {
  const int* x      = (const int*)d_in[0];
  const float* emb  = (const float*)d_in[1];
  const float* pos  = (const float*)d_in[2];
  const float* qkv_w = (const float*)d_in[3];
  const float* qkv_b = (const float*)d_in[4];
  const float* out_w = (const float*)d_in[5];
  const float* out_b = (const float*)d_in[6];
  const float* ln1_s = (const float*)d_in[7];
  const float* ln1_b = (const float*)d_in[8];
  const float* ff1_w = (const float*)d_in[9];
  const float* ff1_b = (const float*)d_in[10];
  const float* ff2_w = (const float*)d_in[11];
  const float* ff2_b = (const float*)d_in[12];
  const float* ln2_s = (const float*)d_in[13];
  const float* ln2_b = (const float*)d_in[14];
  const float* dec_w = (const float*)d_in[15];
  const float* dec_b = (const float*)d_in[16];
  float* out = (float*)d_out;

  char* ws = (char*)d_ws;
  const size_t HBYTES = (size_t)3200 * 1024 * 4;     // 13,107,200
  const size_t BIGBYTES = (size_t)3200 * 4096 * 4;   // 52,428,800
  double* gsum = (double*)ws;
  float* h   = (float*)(ws + 256);
  float* big = (float*)(ws + 256 + HBYTES);
  float* ctx = (float*)(ws + 256 + HBYTES + BIGBYTES);
  float* tmp = (float*)(ws + 256 + HBYTES + BIGBYTES + HBYTES);
  signed char* weff = (signed char*)(ws + 256 + HBYTES + BIGBYTES + 2 * HBYTES);
  // total ws use: 256 + 3*13.1MB + 52.4MB + 32.77MB ~= 119 MiB

  hipMemsetAsync(d_ws, 0, 256, stream);  // zero gsum (ws is NOT re-poisoned between replays)
  absmean_kernel<<<4096, 256, 0, stream>>>(dec_w, gsum);
  quantize_kernel<<<8192, 256, 0, stream>>>(dec_w, gsum, weff);
  embed_kernel<<<3200, 256, 0, stream>>>(x, emb, pos, h);

  const int M = 3200;
  for (int l = 0; l < 2; ++l) {
    gemm_nt<0, float><<<dim3(3072 / 64, M / 64), 256, 0, stream>>>(
        h, qkv_w + (size_t)l * 3072 * 1024, qkv_b + l * 3072, big,
        M, 3072, 1024, 1024, 1024, 3072);
    attn_kernel<<<512, 128, 0, stream>>>(big, ctx);
    gemm_nt<0, float><<<dim3(1024 / 64, M / 64), 256, 0, stream>>>(
        ctx, out_w + (size_t)l * 1024 * 1024, out_b + l * 1024, tmp,
        M, 1024, 1024, 1024, 1024, 1024);
    add_ln_kernel<<<M, 256, 0, stream>>>(h, tmp, ln1_s + l * 1024, ln1_b + l * 1024);
    gemm_nt<1, float><<<dim3(4096 / 64, M / 64), 256, 0, stream>>>(
        h, ff1_w + (size_t)l * 4096 * 1024, ff1_b + l * 4096, big,
        M, 4096, 1024, 1024, 1024, 4096);
    gemm_nt<0, float><<<dim3(1024 / 64, M / 64), 256, 0, stream>>>(
        big, ff2_w + (size_t)l * 1024 * 4096, ff2_b + l * 1024, tmp,
        M, 1024, 4096, 4096, 4096, 1024);
    add_ln_kernel<<<M, 256, 0, stream>>>(h, tmp, ln2_s + l * 1024, ln2_b + l * 1024);
  }
  // ternary decoder: out = h @ w_eff^T + dec_b
  gemm_nt<0, signed char><<<dim3(32000 / 64, M / 64), 256, 0, stream>>>(
      h, weff, dec_b, out, M, 32000, 1024, 1024, 1024, 32000);
}

// Round 2
// 1146.116 us; speedup vs baseline: 4.8072x; 4.8072x over previous
//
#include <hip/hip_runtime.h>
#include <hip/hip_bf16.h>
#include <math.h>

#define B_ 32
#define S_ 100
#define D_ 1024
#define H_ 16
#define L_ 2
#define V_ 32000
#define DF_ 4096
#define HD_ 64

typedef __bf16 bf16x8 __attribute__((ext_vector_type(8)));
typedef float f32x4 __attribute__((ext_vector_type(4)));

__device__ __forceinline__ void async_copy16(const void* g, void* l) {
  __builtin_amdgcn_global_load_lds((const __attribute__((address_space(1))) void*)g,
                                   (__attribute__((address_space(3))) void*)l, 16, 0, 0);
}

// ------------------------------------------------------------------
// g = mean(|dec_w|) in float64 (order-insensitive to ~1e-13 relative)
// ------------------------------------------------------------------
__global__ void absmean_kernel(const float* __restrict__ w, double* __restrict__ out) {
  const long long n = (long long)V_ * D_;
  double s = 0.0;
  long long stride = (long long)gridDim.x * blockDim.x;
  for (long long i = (long long)blockIdx.x * blockDim.x + threadIdx.x; i < n; i += stride)
    s += (double)fabsf(w[i]);
#pragma unroll
  for (int off = 32; off > 0; off >>= 1) s += __shfl_down(s, off);
  __shared__ double sm[4];
  int lane = threadIdx.x & 63, wv = threadIdx.x >> 6;
  if (lane == 0) sm[wv] = s;
  __syncthreads();
  if (threadIdx.x == 0) atomicAdd(out, sm[0] + sm[1] + sm[2] + sm[3]);
}

// packed effective ternary weight as bf16: {q==0:+1, q==+1:-1, q==-1:0}
__global__ void quantize_kernel(const float* __restrict__ w, const double* __restrict__ gsum,
                                __hip_bfloat16* __restrict__ q) {
  const long long n = (long long)V_ * D_;
  double g = (*gsum) / (double)n + 1e-6;
  long long stride = (long long)gridDim.x * blockDim.x;
  for (long long i = (long long)blockIdx.x * blockDim.x + threadIdx.x; i < n; i += stride) {
    double z = (double)w[i] / g;
    double r = rint(z);  // half-to-even, matches np.round
    r = fmin(1.0, fmax(-1.0, r));
    float w_eff = (r == 0.0) ? 1.0f : ((r == 1.0) ? -1.0f : 0.0f);
    q[i] = __float2bfloat16(w_eff);  // exact
  }
}

// fp32 -> bf16 bulk cast (n multiple of 4)
__global__ void cast_kernel(const float* __restrict__ in, __hip_bfloat16* __restrict__ out,
                            long long n4) {
  long long stride = (long long)gridDim.x * blockDim.x;
  for (long long i = (long long)blockIdx.x * blockDim.x + threadIdx.x; i < n4; i += stride) {
    float4 v = ((const float4*)in)[i];
    union { __hip_bfloat16 h[4]; uint2 u; } o;
    o.h[0] = __float2bfloat16(v.x);
    o.h[1] = __float2bfloat16(v.y);
    o.h[2] = __float2bfloat16(v.z);
    o.h[3] = __float2bfloat16(v.w);
    ((uint2*)out)[i] = o.u;
  }
}

// ------------------------------------------------------------------
// h[b,s,:] = emb[x[b,s],:] + pos[s,:]  -> fp32 h and bf16 h_bf
// ------------------------------------------------------------------
__global__ __launch_bounds__(256) void embed_kernel(const int* __restrict__ x,
    const float* __restrict__ emb, const float* __restrict__ pos,
    float* __restrict__ h, __hip_bfloat16* __restrict__ hb) {
  int row = blockIdx.x;  // b*S + s
  int s = row % S_;
  int tok = x[row];
  size_t eb = (size_t)tok * D_, pb = (size_t)s * D_, hb0 = (size_t)row * D_;
#pragma unroll
  for (int i = 0; i < 4; ++i) {
    int d = threadIdx.x + i * 256;
    float v = emb[eb + d] + pos[pb + d];
    h[hb0 + d] = v;
    hb[hb0 + d] = __float2bfloat16(v);
  }
}

// ------------------------------------------------------------------
// bf16 MFMA GEMM (m97 structure): C[M,N] = act(A[M,K] @ B[N,K]^T + bias)
// 128x128 tile, BK=32, 4 waves (2x2 of 64x64), 16x16x32 MFMA.
// ACT: 0=none 1=gelu.  OUTBF: 0 -> fp32 C, 1 -> bf16 C.
// ------------------------------------------------------------------
__device__ __forceinline__ float gelu_exact(float v) {
  return 0.5f * v * (1.0f + erff(v * 0.70710678118654752f));
}

template <int ACT, int OUTBF>
__global__ __launch_bounds__(256) void gemm_bf(const __hip_bfloat16* __restrict__ A,
    const __hip_bfloat16* __restrict__ Bm, const float* __restrict__ bias,
    void* __restrict__ C, int M, int N, int K) {
  __shared__ __bf16 As[128 * 32];
  __shared__ __bf16 Bs[128 * 32];
  int tid = threadIdx.x;
  int lane = tid & 63, wid = tid >> 6;
  int wr = wid >> 1, wc = wid & 1;       // wave -> 64x64 quadrant
  int row0 = blockIdx.y * 128, col0 = blockIdx.x * 128;

  // staging source pointers (advance by 32 each K-step)
  int j0 = wid * 2;
  const __hip_bfloat16* Ag0 = A + (size_t)(row0 + j0 * 16 + (lane >> 2)) * K + (lane & 3) * 8;
  const __hip_bfloat16* Ag1 = A + (size_t)(row0 + (j0 + 1) * 16 + (lane >> 2)) * K + (lane & 3) * 8;
  const __hip_bfloat16* Bg0 = Bm + (size_t)(col0 + j0 * 16 + (lane >> 2)) * K + (lane & 3) * 8;
  const __hip_bfloat16* Bg1 = Bm + (size_t)(col0 + (j0 + 1) * 16 + (lane >> 2)) * K + (lane & 3) * 8;
  __bf16* Al0 = As + j0 * 512;
  __bf16* Al1 = As + (j0 + 1) * 512;
  __bf16* Bl0 = Bs + j0 * 512;
  __bf16* Bl1 = Bs + (j0 + 1) * 512;

  float bias_v[4];
#pragma unroll
  for (int ni = 0; ni < 4; ++ni)
    bias_v[ni] = bias[col0 + wc * 64 + ni * 16 + (lane & 15)];

  f32x4 acc[4][4];
#pragma unroll
  for (int mi = 0; mi < 4; ++mi)
#pragma unroll
    for (int ni = 0; ni < 4; ++ni) acc[mi][ni] = (f32x4){0.f, 0.f, 0.f, 0.f};

  const bf16x8* Asv = reinterpret_cast<const bf16x8*>(As);
  const bf16x8* Bsv = reinterpret_cast<const bf16x8*>(Bs);
  int afr = (wr * 64 + (lane & 15)) * 4 + (lane >> 4);  // in 8-elem units
  int bfr = (wc * 64 + (lane & 15)) * 4 + (lane >> 4);

  for (int k0 = 0; k0 < K; k0 += 32) {
    async_copy16(Ag0, Al0);
    async_copy16(Ag1, Al1);
    async_copy16(Bg0, Bl0);
    async_copy16(Bg1, Bl1);
    Ag0 += 32; Ag1 += 32; Bg0 += 32; Bg1 += 32;
    __syncthreads();  // drains vmcnt: LDS tile visible to all waves
    bf16x8 af[4], bf[4];
#pragma unroll
    for (int mi = 0; mi < 4; ++mi) af[mi] = Asv[afr + mi * 64];
#pragma unroll
    for (int ni = 0; ni < 4; ++ni) bf[ni] = Bsv[bfr + ni * 64];
#pragma unroll
    for (int mi = 0; mi < 4; ++mi)
#pragma unroll
      for (int ni = 0; ni < 4; ++ni)
        acc[mi][ni] = __builtin_amdgcn_mfma_f32_16x16x32_bf16(af[mi], bf[ni], acc[mi][ni], 0, 0, 0);
    __syncthreads();  // compute done before next-tile overwrite
  }

  // epilogue: C row = (lane>>4)*4 + r within 16x16 frag, col = lane&15  [m89 layout]
  float* Cf = (float*)C;
  __hip_bfloat16* Cb = (__hip_bfloat16*)C;
#pragma unroll
  for (int mi = 0; mi < 4; ++mi) {
#pragma unroll
    for (int r = 0; r < 4; ++r) {
      size_t m = row0 + wr * 64 + mi * 16 + (lane >> 4) * 4 + r;
#pragma unroll
      for (int ni = 0; ni < 4; ++ni) {
        size_t n = col0 + wc * 64 + ni * 16 + (lane & 15);
        float v = acc[mi][ni][r] + bias_v[ni];
        if (ACT == 1) v = gelu_exact(v);
        if (OUTBF) Cb[m * N + n] = __float2bfloat16(v);
        else       Cf[m * N + n] = v;
      }
    }
  }
}

// ------------------------------------------------------------------
// Fused attention per (b,h): bf16 in/out, fp32 compute. S=100, hd=64.
// ------------------------------------------------------------------
__global__ __launch_bounds__(128) void attn_kernel(const __hip_bfloat16* __restrict__ qkv,
                                                   __hip_bfloat16* __restrict__ ctx) {
  __shared__ float KV[50][64];
  __shared__ float Sc[100][100];
  int bh = blockIdx.x;  // b*H + h
  int b = bh >> 4, hh = bh & 15;
  int tid = threadIdx.x;
  size_t base = (size_t)b * S_ * (3 * D_);
  int hcol = hh * HD_;
  int r = tid;

  float qa[64];
  if (r < 100) {
    const __hip_bfloat16* qp = qkv + base + (size_t)r * (3 * D_) + hcol;
#pragma unroll
    for (int d0 = 0; d0 < 8; ++d0) {
      union { uint4 u; __hip_bfloat16 h[8]; } uu;
      uu.u = *(const uint4*)(qp + d0 * 8);
#pragma unroll
      for (int j = 0; j < 8; ++j) qa[d0 * 8 + j] = __bfloat162float(uu.h[j]);
    }
  }
  // ---- scores = q.K^T / 8 ----
  for (int t = 0; t < 2; ++t) {
    __syncthreads();
    for (int idx = tid; idx < 3200; idx += 128) {
      int j = idx >> 6, d = idx & 63;
      KV[j][d] = __bfloat162float(qkv[base + (size_t)(t * 50 + j) * (3 * D_) + D_ + hcol + d]);
    }
    __syncthreads();
    if (r < 100) {
      for (int j = 0; j < 50; ++j) {
        float s = 0.f;
#pragma unroll
        for (int d0 = 0; d0 < 16; ++d0) {
          float4 kv = *(const float4*)&KV[j][d0 * 4];
          s += qa[d0 * 4 + 0] * kv.x + qa[d0 * 4 + 1] * kv.y +
               qa[d0 * 4 + 2] * kv.z + qa[d0 * 4 + 3] * kv.w;
        }
        Sc[r][t * 50 + j] = s * 0.125f;
      }
    }
  }
  // ---- softmax along own row ----
  float inv_sum = 0.f;
  if (r < 100) {
    float mx = -1e30f;
    for (int j = 0; j < 100; ++j) mx = fmaxf(mx, Sc[r][j]);
    float sum = 0.f;
    for (int j = 0; j < 100; ++j) {
      float e = expf(Sc[r][j] - mx);
      Sc[r][j] = e;
      sum += e;
    }
    inv_sum = 1.0f / sum;
  }
  // ---- ctx = P.V ----
  float ca[64];
#pragma unroll
  for (int d = 0; d < 64; ++d) ca[d] = 0.f;
  for (int t = 0; t < 2; ++t) {
    __syncthreads();
    for (int idx = tid; idx < 3200; idx += 128) {
      int j = idx >> 6, d = idx & 63;
      KV[j][d] = __bfloat162float(qkv[base + (size_t)(t * 50 + j) * (3 * D_) + 2 * D_ + hcol + d]);
    }
    __syncthreads();
    if (r < 100) {
      for (int j = 0; j < 50; ++j) {
        float p = Sc[r][t * 50 + j];
#pragma unroll
        for (int d0 = 0; d0 < 16; ++d0) {
          float4 kv = *(const float4*)&KV[j][d0 * 4];
          ca[d0 * 4 + 0] += p * kv.x;
          ca[d0 * 4 + 1] += p * kv.y;
          ca[d0 * 4 + 2] += p * kv.z;
          ca[d0 * 4 + 3] += p * kv.w;
        }
      }
    }
  }
  if (r < 100) {
    __hip_bfloat16* cp = ctx + ((size_t)b * S_ + r) * D_ + hcol;
#pragma unroll
    for (int d = 0; d < 64; ++d) cp[d] = __float2bfloat16(ca[d] * inv_sum);
  }
}

// ------------------------------------------------------------------
// h = LN(h + res) * scale + bias   (fp32) and bf16 copy
// ------------------------------------------------------------------
__device__ float block_sum_1024(float v) {
#pragma unroll
  for (int off = 32; off > 0; off >>= 1) v += __shfl_down(v, off);
  __shared__ float sm[4];
  __syncthreads();
  int lane = threadIdx.x & 63, wv = threadIdx.x >> 6;
  if (lane == 0) sm[wv] = v;
  __syncthreads();
  return sm[0] + sm[1] + sm[2] + sm[3];
}

__global__ __launch_bounds__(256) void add_ln_kernel(float* __restrict__ h,
    const float* __restrict__ res, const float* __restrict__ scale,
    const float* __restrict__ bias, __hip_bfloat16* __restrict__ hb) {
  size_t base = (size_t)blockIdx.x * D_;
  int tid = threadIdx.x;
  float x[4];
  float s = 0.f;
#pragma unroll
  for (int i = 0; i < 4; ++i) {
    x[i] = h[base + tid + i * 256] + res[base + tid + i * 256];
    s += x[i];
  }
  float mu = block_sum_1024(s) * (1.0f / 1024.0f);
  float v = 0.f;
#pragma unroll
  for (int i = 0; i < 4; ++i) {
    float d = x[i] - mu;
    v += d * d;
  }
  float var = block_sum_1024(v) * (1.0f / 1024.0f);
  float rs = rsqrtf(var + 1e-5f);
#pragma unroll
  for (int i = 0; i < 4; ++i) {
    int d = tid + i * 256;
    float o = (x[i] - mu) * rs * scale[d] + bias[d];
    h[base + d] = o;
    hb[base + d] = __float2bfloat16(o);
  }
}

// ------------------------------------------------------------------
extern "C" void kernel_launch(void* const* d_in, const int* in_sizes, int n_in,
                              void* d_out, int out_size, void* d_ws, size_t ws_size,
                              hipStream_t stream) {
  const int* x       = (const int*)d_in[0];
  const float* emb   = (const float*)d_in[1];
  const float* pos   = (const float*)d_in[2];
  const float* qkv_w = (const float*)d_in[3];
  const float* qkv_b = (const float*)d_in[4];
  const float* out_w = (const float*)d_in[5];
  const float* out_b = (const float*)d_in[6];
  const float* ln1_s = (const float*)d_in[7];
  const float* ln1_b = (const float*)d_in[8];
  const float* ff1_w = (const float*)d_in[9];
  const float* ff1_b = (const float*)d_in[10];
  const float* ff2_w = (const float*)d_in[11];
  const float* ff2_b = (const float*)d_in[12];
  const float* ln2_s = (const float*)d_in[13];
  const float* ln2_b = (const float*)d_in[14];
  const float* dec_w = (const float*)d_in[15];
  const float* dec_b = (const float*)d_in[16];
  float* out = (float*)d_out;

  char* ws = (char*)d_ws;
  size_t off = 0;
  auto alloc = [&](size_t bytes) { void* p = ws + off; off += (bytes + 255) & ~(size_t)255; return p; };
  double* gsum            = (double*)alloc(256);
  float* h                = (float*)alloc((size_t)3200 * 1024 * 4);
  __hip_bfloat16* h_bf    = (__hip_bfloat16*)alloc((size_t)3200 * 1024 * 2);
  float* tmp              = (float*)alloc((size_t)3200 * 1024 * 4);
  __hip_bfloat16* ctx_bf  = (__hip_bfloat16*)alloc((size_t)3200 * 1024 * 2);
  __hip_bfloat16* big_bf  = (__hip_bfloat16*)alloc((size_t)3200 * 4096 * 2);  // qkv out / ff1 out
  __hip_bfloat16* weff    = (__hip_bfloat16*)alloc((size_t)32000 * 1024 * 2);
  __hip_bfloat16* qkvw_bf = (__hip_bfloat16*)alloc((size_t)2 * 3072 * 1024 * 2);
  __hip_bfloat16* outw_bf = (__hip_bfloat16*)alloc((size_t)2 * 1024 * 1024 * 2);
  __hip_bfloat16* ff1w_bf = (__hip_bfloat16*)alloc((size_t)2 * 4096 * 1024 * 2);
  __hip_bfloat16* ff2w_bf = (__hip_bfloat16*)alloc((size_t)2 * 1024 * 4096 * 2);
  // total ~182 MiB

  hipMemsetAsync(gsum, 0, 256, stream);  // ws not re-poisoned between replays
  absmean_kernel<<<4096, 256, 0, stream>>>(dec_w, gsum);
  quantize_kernel<<<8192, 256, 0, stream>>>(dec_w, gsum, weff);
  cast_kernel<<<2048, 256, 0, stream>>>(qkv_w, qkvw_bf, (long long)2 * 3072 * 1024 / 4);
  cast_kernel<<<2048, 256, 0, stream>>>(out_w, outw_bf, (long long)2 * 1024 * 1024 / 4);
  cast_kernel<<<2048, 256, 0, stream>>>(ff1_w, ff1w_bf, (long long)2 * 4096 * 1024 / 4);
  cast_kernel<<<2048, 256, 0, stream>>>(ff2_w, ff2w_bf, (long long)2 * 1024 * 4096 / 4);
  embed_kernel<<<3200, 256, 0, stream>>>(x, emb, pos, h, h_bf);

  const int M = 3200;
  for (int l = 0; l < 2; ++l) {
    gemm_bf<0, 1><<<dim3(3072 / 128, M / 128), 256, 0, stream>>>(
        h_bf, qkvw_bf + (size_t)l * 3072 * 1024, qkv_b + l * 3072, big_bf, M, 3072, 1024);
    attn_kernel<<<512, 128, 0, stream>>>(big_bf, ctx_bf);
    gemm_bf<0, 0><<<dim3(1024 / 128, M / 128), 256, 0, stream>>>(
        ctx_bf, outw_bf + (size_t)l * 1024 * 1024, out_b + l * 1024, tmp, M, 1024, 1024);
    add_ln_kernel<<<M, 256, 0, stream>>>(h, tmp, ln1_s + l * 1024, ln1_b + l * 1024, h_bf);
    gemm_bf<1, 1><<<dim3(4096 / 128, M / 128), 256, 0, stream>>>(
        h_bf, ff1w_bf + (size_t)l * 4096 * 1024, ff1_b + l * 4096, big_bf, M, 4096, 1024);
    gemm_bf<0, 0><<<dim3(1024 / 128, M / 128), 256, 0, stream>>>(
        big_bf, ff2w_bf + (size_t)l * 1024 * 4096, ff2_b + l * 1024, tmp, M, 1024, 4096);
    add_ln_kernel<<<M, 256, 0, stream>>>(h, tmp, ln2_s + l * 1024, ln2_b + l * 1024, h_bf);
  }
  // ternary decoder: out = h @ w_eff^T + dec_b
  gemm_bf<0, 0><<<dim3(32000 / 128, M / 128), 256, 0, stream>>>(
      h_bf, weff, dec_b, out, M, 32000, 1024);
}

// Round 3
// 1119.857 us; speedup vs baseline: 4.9199x; 1.0234x over previous
//
#include <hip/hip_runtime.h>
#include <hip/hip_bf16.h>
#include <math.h>

#define B_ 32
#define S_ 100
#define D_ 1024
#define H_ 16
#define L_ 2
#define V_ 32000
#define DF_ 4096
#define HD_ 64

typedef __bf16 bf16x8 __attribute__((ext_vector_type(8)));
typedef float f32x4 __attribute__((ext_vector_type(4)));

__device__ __forceinline__ void async_copy16(const void* g, void* l) {
  __builtin_amdgcn_global_load_lds((const __attribute__((address_space(1))) void*)g,
                                   (__attribute__((address_space(3))) void*)l, 16, 0, 0);
}

// ------------------------------------------------------------------
// g = mean(|dec_w|) in float64 (order-insensitive to ~1e-13 relative)
// ------------------------------------------------------------------
__global__ void absmean_kernel(const float* __restrict__ w, double* __restrict__ out) {
  const long long n4 = (long long)V_ * D_ / 4;
  double s = 0.0;
  long long stride = (long long)gridDim.x * blockDim.x;
  for (long long i = (long long)blockIdx.x * blockDim.x + threadIdx.x; i < n4; i += stride) {
    float4 v = ((const float4*)w)[i];
    s += (double)fabsf(v.x) + (double)fabsf(v.y) + (double)fabsf(v.z) + (double)fabsf(v.w);
  }
#pragma unroll
  for (int off = 32; off > 0; off >>= 1) s += __shfl_down(s, off);
  __shared__ double sm[4];
  int lane = threadIdx.x & 63, wv = threadIdx.x >> 6;
  if (lane == 0) sm[wv] = s;
  __syncthreads();
  if (threadIdx.x == 0) atomicAdd(out, sm[0] + sm[1] + sm[2] + sm[3]);
}

// packed effective ternary weight as bf16: {q==0:+1, q==+1:-1, q==-1:0}
__global__ void quantize_kernel(const float* __restrict__ w, const double* __restrict__ gsum,
                                __hip_bfloat16* __restrict__ q) {
  const long long n4 = (long long)V_ * D_ / 4;
  double g = (*gsum) / ((double)V_ * D_) + 1e-6;
  long long stride = (long long)gridDim.x * blockDim.x;
  for (long long i = (long long)blockIdx.x * blockDim.x + threadIdx.x; i < n4; i += stride) {
    float4 v = ((const float4*)w)[i];
    union { __hip_bfloat16 h[4]; uint2 u; } o;
    float vv[4] = {v.x, v.y, v.z, v.w};
#pragma unroll
    for (int j = 0; j < 4; ++j) {
      double r = rint((double)vv[j] / g);  // half-to-even, matches np.round
      r = fmin(1.0, fmax(-1.0, r));
      float w_eff = (r == 0.0) ? 1.0f : ((r == 1.0) ? -1.0f : 0.0f);
      o.h[j] = __float2bfloat16(w_eff);  // exact
    }
    ((uint2*)q)[i] = o.u;
  }
}

// fp32 -> bf16 bulk cast (n multiple of 4)
__global__ void cast_kernel(const float* __restrict__ in, __hip_bfloat16* __restrict__ out,
                            long long n4) {
  long long stride = (long long)gridDim.x * blockDim.x;
  for (long long i = (long long)blockIdx.x * blockDim.x + threadIdx.x; i < n4; i += stride) {
    float4 v = ((const float4*)in)[i];
    union { __hip_bfloat16 h[4]; uint2 u; } o;
    o.h[0] = __float2bfloat16(v.x);
    o.h[1] = __float2bfloat16(v.y);
    o.h[2] = __float2bfloat16(v.z);
    o.h[3] = __float2bfloat16(v.w);
    ((uint2*)out)[i] = o.u;
  }
}

// ------------------------------------------------------------------
// h[b,s,:] = emb[x[b,s],:] + pos[s,:]  -> fp32 h and bf16 h_bf
// ------------------------------------------------------------------
__global__ __launch_bounds__(256) void embed_kernel(const int* __restrict__ x,
    const float* __restrict__ emb, const float* __restrict__ pos,
    float* __restrict__ h, __hip_bfloat16* __restrict__ hb) {
  int row = blockIdx.x;  // b*S + s
  int s = row % S_;
  int tok = x[row];
  size_t eb = (size_t)tok * D_, pb = (size_t)s * D_, hb0 = (size_t)row * D_;
#pragma unroll
  for (int i = 0; i < 4; ++i) {
    int d = threadIdx.x + i * 256;
    float v = emb[eb + d] + pos[pb + d];
    h[hb0 + d] = v;
    hb[hb0 + d] = __float2bfloat16(v);
  }
}

// ------------------------------------------------------------------
// bf16 MFMA GEMM (m97 structure): C[M,N] = act(A[M,K] @ B[N,K]^T + bias)
// 128x128 tile, BK=32, 4 waves (2x2 of 64x64), 16x16x32 MFMA.
// Grid: (M/128, N/128) with blockIdx.x = ROW tile (M fast-varying) so that
// consecutive blocks share one 256KB B-panel via L2 (B fetched ~once).
// ------------------------------------------------------------------
__device__ __forceinline__ float gelu_exact(float v) {
  return 0.5f * v * (1.0f + erff(v * 0.70710678118654752f));
}

template <int ACT, int OUTBF>
__global__ __launch_bounds__(256) void gemm_bf(const __hip_bfloat16* __restrict__ A,
    const __hip_bfloat16* __restrict__ Bm, const float* __restrict__ bias,
    void* __restrict__ C, int M, int N, int K) {
  __shared__ __bf16 As[128 * 32];
  __shared__ __bf16 Bs[128 * 32];
  int tid = threadIdx.x;
  int lane = tid & 63, wid = tid >> 6;
  int wr = wid >> 1, wc = wid & 1;  // wave -> 64x64 quadrant
  int row0 = blockIdx.x * 128, col0 = blockIdx.y * 128;

  // staging source pointers (advance by 32 each K-step)
  int j0 = wid * 2;
  const __hip_bfloat16* Ag0 = A + (size_t)(row0 + j0 * 16 + (lane >> 2)) * K + (lane & 3) * 8;
  const __hip_bfloat16* Ag1 = A + (size_t)(row0 + (j0 + 1) * 16 + (lane >> 2)) * K + (lane & 3) * 8;
  const __hip_bfloat16* Bg0 = Bm + (size_t)(col0 + j0 * 16 + (lane >> 2)) * K + (lane & 3) * 8;
  const __hip_bfloat16* Bg1 = Bm + (size_t)(col0 + (j0 + 1) * 16 + (lane >> 2)) * K + (lane & 3) * 8;
  __bf16* Al0 = As + j0 * 512;
  __bf16* Al1 = As + (j0 + 1) * 512;
  __bf16* Bl0 = Bs + j0 * 512;
  __bf16* Bl1 = Bs + (j0 + 1) * 512;

  float bias_v[4];
#pragma unroll
  for (int ni = 0; ni < 4; ++ni)
    bias_v[ni] = bias[col0 + wc * 64 + ni * 16 + (lane & 15)];

  f32x4 acc[4][4];
#pragma unroll
  for (int mi = 0; mi < 4; ++mi)
#pragma unroll
    for (int ni = 0; ni < 4; ++ni) acc[mi][ni] = (f32x4){0.f, 0.f, 0.f, 0.f};

  const bf16x8* Asv = reinterpret_cast<const bf16x8*>(As);
  const bf16x8* Bsv = reinterpret_cast<const bf16x8*>(Bs);
  int afr = (wr * 64 + (lane & 15)) * 4 + (lane >> 4);  // in 8-elem units
  int bfr = (wc * 64 + (lane & 15)) * 4 + (lane >> 4);

  for (int k0 = 0; k0 < K; k0 += 32) {
    async_copy16(Ag0, Al0);
    async_copy16(Ag1, Al1);
    async_copy16(Bg0, Bl0);
    async_copy16(Bg1, Bl1);
    Ag0 += 32; Ag1 += 32; Bg0 += 32; Bg1 += 32;
    __syncthreads();  // drains vmcnt: LDS tile visible to all waves
    bf16x8 af[4], bf[4];
#pragma unroll
    for (int mi = 0; mi < 4; ++mi) af[mi] = Asv[afr + mi * 64];
#pragma unroll
    for (int ni = 0; ni < 4; ++ni) bf[ni] = Bsv[bfr + ni * 64];
#pragma unroll
    for (int mi = 0; mi < 4; ++mi)
#pragma unroll
      for (int ni = 0; ni < 4; ++ni)
        acc[mi][ni] = __builtin_amdgcn_mfma_f32_16x16x32_bf16(af[mi], bf[ni], acc[mi][ni], 0, 0, 0);
    __syncthreads();  // compute done before next-tile overwrite
  }

  // epilogue: C row = (lane>>4)*4 + r within 16x16 frag, col = lane&15  [m89 layout]
  float* Cf = (float*)C;
  __hip_bfloat16* Cb = (__hip_bfloat16*)C;
#pragma unroll
  for (int mi = 0; mi < 4; ++mi) {
#pragma unroll
    for (int r = 0; r < 4; ++r) {
      size_t m = row0 + wr * 64 + mi * 16 + (lane >> 4) * 4 + r;
#pragma unroll
      for (int ni = 0; ni < 4; ++ni) {
        size_t n = col0 + wc * 64 + ni * 16 + (lane & 15);
        float v = acc[mi][ni][r] + bias_v[ni];
        if (ACT == 1) v = gelu_exact(v);
        if (OUTBF) Cb[m * N + n] = __float2bfloat16(v);
        else       Cf[m * N + n] = v;
      }
    }
  }
}

// ------------------------------------------------------------------
// Fused attention per (b,h): bf16 in/out, fp32 compute. S=100, hd=64.
// ------------------------------------------------------------------
__global__ __launch_bounds__(128) void attn_kernel(const __hip_bfloat16* __restrict__ qkv,
                                                   __hip_bfloat16* __restrict__ ctx) {
  __shared__ float KV[50][64];
  __shared__ float Sc[100][100];
  int bh = blockIdx.x;  // b*H + h
  int b = bh >> 4, hh = bh & 15;
  int tid = threadIdx.x;
  size_t base = (size_t)b * S_ * (3 * D_);
  int hcol = hh * HD_;
  int r = tid;

  float qa[64];
  if (r < 100) {
    const __hip_bfloat16* qp = qkv + base + (size_t)r * (3 * D_) + hcol;
#pragma unroll
    for (int d0 = 0; d0 < 8; ++d0) {
      union { uint4 u; __hip_bfloat16 h[8]; } uu;
      uu.u = *(const uint4*)(qp + d0 * 8);
#pragma unroll
      for (int j = 0; j < 8; ++j) qa[d0 * 8 + j] = __bfloat162float(uu.h[j]);
    }
  }
  // ---- scores = q.K^T / 8 ----
  for (int t = 0; t < 2; ++t) {
    __syncthreads();
    // vectorized staging: 50 rows x 8 uint4 (8 bf16 each) = 400 loads
    for (int idx = tid; idx < 400; idx += 128) {
      int j = idx >> 3, d8 = idx & 7;
      union { uint4 u; __hip_bfloat16 h[8]; } uu;
      uu.u = *(const uint4*)(qkv + base + (size_t)(t * 50 + j) * (3 * D_) + D_ + hcol + d8 * 8);
#pragma unroll
      for (int e = 0; e < 8; ++e) KV[j][d8 * 8 + e] = __bfloat162float(uu.h[e]);
    }
    __syncthreads();
    if (r < 100) {
      for (int j = 0; j < 50; ++j) {
        float s = 0.f;
#pragma unroll
        for (int d0 = 0; d0 < 16; ++d0) {
          float4 kv = *(const float4*)&KV[j][d0 * 4];
          s += qa[d0 * 4 + 0] * kv.x + qa[d0 * 4 + 1] * kv.y +
               qa[d0 * 4 + 2] * kv.z + qa[d0 * 4 + 3] * kv.w;
        }
        Sc[r][t * 50 + j] = s * 0.125f;
      }
    }
  }
  // ---- softmax along own row ----
  float inv_sum = 0.f;
  if (r < 100) {
    float mx = -1e30f;
    for (int j = 0; j < 100; ++j) mx = fmaxf(mx, Sc[r][j]);
    float sum = 0.f;
    for (int j = 0; j < 100; ++j) {
      float e = expf(Sc[r][j] - mx);
      Sc[r][j] = e;
      sum += e;
    }
    inv_sum = 1.0f / sum;
  }
  // ---- ctx = P.V ----
  float ca[64];
#pragma unroll
  for (int d = 0; d < 64; ++d) ca[d] = 0.f;
  for (int t = 0; t < 2; ++t) {
    __syncthreads();
    for (int idx = tid; idx < 400; idx += 128) {
      int j = idx >> 3, d8 = idx & 7;
      union { uint4 u; __hip_bfloat16 h[8]; } uu;
      uu.u = *(const uint4*)(qkv + base + (size_t)(t * 50 + j) * (3 * D_) + 2 * D_ + hcol + d8 * 8);
#pragma unroll
      for (int e = 0; e < 8; ++e) KV[j][d8 * 8 + e] = __bfloat162float(uu.h[e]);
    }
    __syncthreads();
    if (r < 100) {
      for (int j = 0; j < 50; ++j) {
        float p = Sc[r][t * 50 + j];
#pragma unroll
        for (int d0 = 0; d0 < 16; ++d0) {
          float4 kv = *(const float4*)&KV[j][d0 * 4];
          ca[d0 * 4 + 0] += p * kv.x;
          ca[d0 * 4 + 1] += p * kv.y;
          ca[d0 * 4 + 2] += p * kv.z;
          ca[d0 * 4 + 3] += p * kv.w;
        }
      }
    }
  }
  if (r < 100) {
    __hip_bfloat16* cp = ctx + ((size_t)b * S_ + r) * D_ + hcol;
#pragma unroll
    for (int d = 0; d < 64; ++d) cp[d] = __float2bfloat16(ca[d] * inv_sum);
  }
}

// ------------------------------------------------------------------
// h = LN(h + res) * scale + bias   (fp32) and bf16 copy
// ------------------------------------------------------------------
__device__ float block_sum_1024(float v) {
#pragma unroll
  for (int off = 32; off > 0; off >>= 1) v += __shfl_down(v, off);
  __shared__ float sm[4];
  __syncthreads();
  int lane = threadIdx.x & 63, wv = threadIdx.x >> 6;
  if (lane == 0) sm[wv] = v;
  __syncthreads();
  return sm[0] + sm[1] + sm[2] + sm[3];
}

__global__ __launch_bounds__(256) void add_ln_kernel(float* __restrict__ h,
    const float* __restrict__ res, const float* __restrict__ scale,
    const float* __restrict__ bias, __hip_bfloat16* __restrict__ hb) {
  size_t base = (size_t)blockIdx.x * D_;
  int tid = threadIdx.x;
  float x[4];
  float s = 0.f;
#pragma unroll
  for (int i = 0; i < 4; ++i) {
    x[i] = h[base + tid + i * 256] + res[base + tid + i * 256];
    s += x[i];
  }
  float mu = block_sum_1024(s) * (1.0f / 1024.0f);
  float v = 0.f;
#pragma unroll
  for (int i = 0; i < 4; ++i) {
    float d = x[i] - mu;
    v += d * d;
  }
  float var = block_sum_1024(v) * (1.0f / 1024.0f);
  float rs = rsqrtf(var + 1e-5f);
#pragma unroll
  for (int i = 0; i < 4; ++i) {
    int d = tid + i * 256;
    float o = (x[i] - mu) * rs * scale[d] + bias[d];
    h[base + d] = o;
    hb[base + d] = __float2bfloat16(o);
  }
}

// ------------------------------------------------------------------
extern "C" void kernel_launch(void* const* d_in, const int* in_sizes, int n_in,
                              void* d_out, int out_size, void* d_ws, size_t ws_size,
                              hipStream_t stream) {
  const int* x       = (const int*)d_in[0];
  const float* emb   = (const float*)d_in[1];
  const float* pos   = (const float*)d_in[2];
  const float* qkv_w = (const float*)d_in[3];
  const float* qkv_b = (const float*)d_in[4];
  const float* out_w = (const float*)d_in[5];
  const float* out_b = (const float*)d_in[6];
  const float* ln1_s = (const float*)d_in[7];
  const float* ln1_b = (const float*)d_in[8];
  const float* ff1_w = (const float*)d_in[9];
  const float* ff1_b = (const float*)d_in[10];
  const float* ff2_w = (const float*)d_in[11];
  const float* ff2_b = (const float*)d_in[12];
  const float* ln2_s = (const float*)d_in[13];
  const float* ln2_b = (const float*)d_in[14];
  const float* dec_w = (const float*)d_in[15];
  const float* dec_b = (const float*)d_in[16];
  float* out = (float*)d_out;

  char* ws = (char*)d_ws;
  size_t off = 0;
  auto alloc = [&](size_t bytes) { void* p = ws + off; off += (bytes + 255) & ~(size_t)255; return p; };
  double* gsum            = (double*)alloc(256);
  float* h                = (float*)alloc((size_t)3200 * 1024 * 4);
  __hip_bfloat16* h_bf    = (__hip_bfloat16*)alloc((size_t)3200 * 1024 * 2);
  float* tmp              = (float*)alloc((size_t)3200 * 1024 * 4);
  __hip_bfloat16* ctx_bf  = (__hip_bfloat16*)alloc((size_t)3200 * 1024 * 2);
  __hip_bfloat16* big_bf  = (__hip_bfloat16*)alloc((size_t)3200 * 4096 * 2);  // qkv out / ff1 out
  __hip_bfloat16* weff    = (__hip_bfloat16*)alloc((size_t)32000 * 1024 * 2);
  __hip_bfloat16* qkvw_bf = (__hip_bfloat16*)alloc((size_t)2 * 3072 * 1024 * 2);
  __hip_bfloat16* outw_bf = (__hip_bfloat16*)alloc((size_t)2 * 1024 * 1024 * 2);
  __hip_bfloat16* ff1w_bf = (__hip_bfloat16*)alloc((size_t)2 * 4096 * 1024 * 2);
  __hip_bfloat16* ff2w_bf = (__hip_bfloat16*)alloc((size_t)2 * 1024 * 4096 * 2);

  hipMemsetAsync(gsum, 0, 256, stream);  // ws not re-poisoned between replays
  absmean_kernel<<<2048, 256, 0, stream>>>(dec_w, gsum);
  quantize_kernel<<<4096, 256, 0, stream>>>(dec_w, gsum, weff);
  cast_kernel<<<2048, 256, 0, stream>>>(qkv_w, qkvw_bf, (long long)2 * 3072 * 1024 / 4);
  cast_kernel<<<2048, 256, 0, stream>>>(out_w, outw_bf, (long long)2 * 1024 * 1024 / 4);
  cast_kernel<<<2048, 256, 0, stream>>>(ff1_w, ff1w_bf, (long long)2 * 4096 * 1024 / 4);
  cast_kernel<<<2048, 256, 0, stream>>>(ff2_w, ff2w_bf, (long long)2 * 1024 * 4096 / 4);
  embed_kernel<<<3200, 256, 0, stream>>>(x, emb, pos, h, h_bf);

  const int M = 3200;
  for (int l = 0; l < 2; ++l) {
    gemm_bf<0, 1><<<dim3(M / 128, 3072 / 128), 256, 0, stream>>>(
        h_bf, qkvw_bf + (size_t)l * 3072 * 1024, qkv_b + l * 3072, big_bf, M, 3072, 1024);
    attn_kernel<<<512, 128, 0, stream>>>(big_bf, ctx_bf);
    gemm_bf<0, 0><<<dim3(M / 128, 1024 / 128), 256, 0, stream>>>(
        ctx_bf, outw_bf + (size_t)l * 1024 * 1024, out_b + l * 1024, tmp, M, 1024, 1024);
    add_ln_kernel<<<M, 256, 0, stream>>>(h, tmp, ln1_s + l * 1024, ln1_b + l * 1024, h_bf);
    gemm_bf<1, 1><<<dim3(M / 128, 4096 / 128), 256, 0, stream>>>(
        h_bf, ff1w_bf + (size_t)l * 4096 * 1024, ff1_b + l * 4096, big_bf, M, 4096, 1024);
    gemm_bf<0, 0><<<dim3(M / 128, 1024 / 128), 256, 0, stream>>>(
        big_bf, ff2w_bf + (size_t)l * 1024 * 4096, ff2_b + l * 1024, tmp, M, 1024, 4096);
    add_ln_kernel<<<M, 256, 0, stream>>>(h, tmp, ln2_s + l * 1024, ln2_b + l * 1024, h_bf);
  }
  // ternary decoder: out = h @ w_eff^T + dec_b  (M fast-varying grid)
  gemm_bf<0, 0><<<dim3(M / 128, 32000 / 128), 256, 0, stream>>>(
      h_bf, weff, dec_b, out, M, 32000, 1024);
}

// Round 4
// 1110.254 us; speedup vs baseline: 4.9625x; 1.0086x over previous
//
#include <hip/hip_runtime.h>
#include <hip/hip_bf16.h>
#include <math.h>

#define B_ 32
#define S_ 100
#define D_ 1024
#define H_ 16
#define L_ 2
#define V_ 32000
#define DF_ 4096
#define HD_ 64

typedef __bf16 bf16x8 __attribute__((ext_vector_type(8)));
typedef float f32x4 __attribute__((ext_vector_type(4)));

__device__ __forceinline__ void async_copy16(const void* g, void* l) {
  __builtin_amdgcn_global_load_lds((const __attribute__((address_space(1))) void*)g,
                                   (__attribute__((address_space(3))) void*)l, 16, 0, 0);
}

// ------------------------------------------------------------------
// g = mean(|dec_w|) in float64 (order-insensitive to ~1e-13 relative)
// ------------------------------------------------------------------
__global__ void absmean_kernel(const float* __restrict__ w, double* __restrict__ out) {
  const long long n4 = (long long)V_ * D_ / 4;
  double s = 0.0;
  long long stride = (long long)gridDim.x * blockDim.x;
  for (long long i = (long long)blockIdx.x * blockDim.x + threadIdx.x; i < n4; i += stride) {
    float4 v = ((const float4*)w)[i];
    s += (double)fabsf(v.x) + (double)fabsf(v.y) + (double)fabsf(v.z) + (double)fabsf(v.w);
  }
#pragma unroll
  for (int off = 32; off > 0; off >>= 1) s += __shfl_down(s, off);
  __shared__ double sm[4];
  int lane = threadIdx.x & 63, wv = threadIdx.x >> 6;
  if (lane == 0) sm[wv] = s;
  __syncthreads();
  if (threadIdx.x == 0) atomicAdd(out, sm[0] + sm[1] + sm[2] + sm[3]);
}

// packed effective ternary weight as bf16: {q==0:+1, q==+1:-1, q==-1:0}
__global__ void quantize_kernel(const float* __restrict__ w, const double* __restrict__ gsum,
                                __hip_bfloat16* __restrict__ q) {
  const long long n4 = (long long)V_ * D_ / 4;
  double g = (*gsum) / ((double)V_ * D_) + 1e-6;
  long long stride = (long long)gridDim.x * blockDim.x;
  for (long long i = (long long)blockIdx.x * blockDim.x + threadIdx.x; i < n4; i += stride) {
    float4 v = ((const float4*)w)[i];
    union { __hip_bfloat16 h[4]; uint2 u; } o;
    float vv[4] = {v.x, v.y, v.z, v.w};
#pragma unroll
    for (int j = 0; j < 4; ++j) {
      double r = rint((double)vv[j] / g);  // half-to-even, matches np.round
      r = fmin(1.0, fmax(-1.0, r));
      float w_eff = (r == 0.0) ? 1.0f : ((r == 1.0) ? -1.0f : 0.0f);
      o.h[j] = __float2bfloat16(w_eff);  // exact
    }
    ((uint2*)q)[i] = o.u;
  }
}

// fp32 -> bf16 bulk cast (n multiple of 4)
__global__ void cast_kernel(const float* __restrict__ in, __hip_bfloat16* __restrict__ out,
                            long long n4) {
  long long stride = (long long)gridDim.x * blockDim.x;
  for (long long i = (long long)blockIdx.x * blockDim.x + threadIdx.x; i < n4; i += stride) {
    float4 v = ((const float4*)in)[i];
    union { __hip_bfloat16 h[4]; uint2 u; } o;
    o.h[0] = __float2bfloat16(v.x);
    o.h[1] = __float2bfloat16(v.y);
    o.h[2] = __float2bfloat16(v.z);
    o.h[3] = __float2bfloat16(v.w);
    ((uint2*)out)[i] = o.u;
  }
}

// ------------------------------------------------------------------
// h[b,s,:] = emb[x[b,s],:] + pos[s,:]  -> fp32 h and bf16 h_bf
// ------------------------------------------------------------------
__global__ __launch_bounds__(256) void embed_kernel(const int* __restrict__ x,
    const float* __restrict__ emb, const float* __restrict__ pos,
    float* __restrict__ h, __hip_bfloat16* __restrict__ hb) {
  int row = blockIdx.x;  // b*S + s
  int s = row % S_;
  int tok = x[row];
  size_t eb = (size_t)tok * D_, pb = (size_t)s * D_, hb0 = (size_t)row * D_;
#pragma unroll
  for (int i = 0; i < 4; ++i) {
    int d = threadIdx.x + i * 256;
    float v = emb[eb + d] + pos[pb + d];
    h[hb0 + d] = v;
    hb[hb0 + d] = __float2bfloat16(v);
  }
}

// ------------------------------------------------------------------
// bf16 MFMA GEMM (m97 structure): C[M,N] = act(A[M,K] @ B[N,K]^T + bias)
// 128x128 tile, BK=32, 4 waves (2x2 of 64x64), 16x16x32 MFMA.
// Bijective XCD swizzle (m204): each XCD owns a contiguous chunk of the
// M-fastest logical order, so one N-panel's M-tiles stay on ONE XCD's L2
// and B is fetched ~once chip-wide (consecutive hw blockIds round-robin
// across the 8 non-coherent per-XCD L2s otherwise).
// ------------------------------------------------------------------
__device__ __forceinline__ float gelu_exact(float v) {
  return 0.5f * v * (1.0f + erff(v * 0.70710678118654752f));
}

template <int ACT, int OUTBF>
__global__ __launch_bounds__(256) void gemm_bf(const __hip_bfloat16* __restrict__ A,
    const __hip_bfloat16* __restrict__ Bm, const float* __restrict__ bias,
    void* __restrict__ C, int M, int N, int K) {
  __shared__ __bf16 As[128 * 32];
  __shared__ __bf16 Bs[128 * 32];
  int tid = threadIdx.x;
  int lane = tid & 63, wid = tid >> 6;
  int wr = wid >> 1, wc = wid & 1;  // wave -> 64x64 quadrant

  // ---- bijective XCD swizzle (T1 / m204) ----
  int nwg = gridDim.x * gridDim.y;
  int orig = blockIdx.y * gridDim.x + blockIdx.x;
  int q = nwg >> 3, r = nwg & 7;
  int xcd = orig & 7, local = orig >> 3;
  int wgid = (xcd < r ? xcd * (q + 1) : r * (q + 1) + (xcd - r) * q) + local;
  int mtile = wgid % gridDim.x;  // gridDim.x = M/128 (M fastest)
  int ntile = wgid / gridDim.x;
  int row0 = mtile * 128, col0 = ntile * 128;

  // staging source pointers (advance by 32 each K-step)
  int j0 = wid * 2;
  const __hip_bfloat16* Ag0 = A + (size_t)(row0 + j0 * 16 + (lane >> 2)) * K + (lane & 3) * 8;
  const __hip_bfloat16* Ag1 = A + (size_t)(row0 + (j0 + 1) * 16 + (lane >> 2)) * K + (lane & 3) * 8;
  const __hip_bfloat16* Bg0 = Bm + (size_t)(col0 + j0 * 16 + (lane >> 2)) * K + (lane & 3) * 8;
  const __hip_bfloat16* Bg1 = Bm + (size_t)(col0 + (j0 + 1) * 16 + (lane >> 2)) * K + (lane & 3) * 8;
  __bf16* Al0 = As + j0 * 512;
  __bf16* Al1 = As + (j0 + 1) * 512;
  __bf16* Bl0 = Bs + j0 * 512;
  __bf16* Bl1 = Bs + (j0 + 1) * 512;

  float bias_v[4];
#pragma unroll
  for (int ni = 0; ni < 4; ++ni)
    bias_v[ni] = bias[col0 + wc * 64 + ni * 16 + (lane & 15)];

  f32x4 acc[4][4];
#pragma unroll
  for (int mi = 0; mi < 4; ++mi)
#pragma unroll
    for (int ni = 0; ni < 4; ++ni) acc[mi][ni] = (f32x4){0.f, 0.f, 0.f, 0.f};

  const bf16x8* Asv = reinterpret_cast<const bf16x8*>(As);
  const bf16x8* Bsv = reinterpret_cast<const bf16x8*>(Bs);
  int afr = (wr * 64 + (lane & 15)) * 4 + (lane >> 4);  // in 8-elem units
  int bfr = (wc * 64 + (lane & 15)) * 4 + (lane >> 4);

  for (int k0 = 0; k0 < K; k0 += 32) {
    async_copy16(Ag0, Al0);
    async_copy16(Ag1, Al1);
    async_copy16(Bg0, Bl0);
    async_copy16(Bg1, Bl1);
    Ag0 += 32; Ag1 += 32; Bg0 += 32; Bg1 += 32;
    __syncthreads();  // drains vmcnt: LDS tile visible to all waves
    bf16x8 af[4], bf[4];
#pragma unroll
    for (int mi = 0; mi < 4; ++mi) af[mi] = Asv[afr + mi * 64];
#pragma unroll
    for (int ni = 0; ni < 4; ++ni) bf[ni] = Bsv[bfr + ni * 64];
#pragma unroll
    for (int mi = 0; mi < 4; ++mi)
#pragma unroll
      for (int ni = 0; ni < 4; ++ni)
        acc[mi][ni] = __builtin_amdgcn_mfma_f32_16x16x32_bf16(af[mi], bf[ni], acc[mi][ni], 0, 0, 0);
    __syncthreads();  // compute done before next-tile overwrite
  }

  // epilogue: C row = (lane>>4)*4 + r within 16x16 frag, col = lane&15  [m89 layout]
  float* Cf = (float*)C;
  __hip_bfloat16* Cb = (__hip_bfloat16*)C;
#pragma unroll
  for (int mi = 0; mi < 4; ++mi) {
#pragma unroll
    for (int r2 = 0; r2 < 4; ++r2) {
      size_t m = row0 + wr * 64 + mi * 16 + (lane >> 4) * 4 + r2;
#pragma unroll
      for (int ni = 0; ni < 4; ++ni) {
        size_t n = col0 + wc * 64 + ni * 16 + (lane & 15);
        float v = acc[mi][ni][r2] + bias_v[ni];
        if (ACT == 1) v = gelu_exact(v);
        if (OUTBF) Cb[m * N + n] = __float2bfloat16(v);
        else       Cf[m * N + n] = v;
      }
    }
  }
}

// ------------------------------------------------------------------
// Fused attention per (b,h): bf16 in/out, fp32 compute. S=100, hd=64.
// ------------------------------------------------------------------
__global__ __launch_bounds__(128) void attn_kernel(const __hip_bfloat16* __restrict__ qkv,
                                                   __hip_bfloat16* __restrict__ ctx) {
  __shared__ float KV[50][64];
  __shared__ float Sc[100][100];
  int bh = blockIdx.x;  // b*H + h
  int b = bh >> 4, hh = bh & 15;
  int tid = threadIdx.x;
  size_t base = (size_t)b * S_ * (3 * D_);
  int hcol = hh * HD_;
  int r = tid;

  float qa[64];
  if (r < 100) {
    const __hip_bfloat16* qp = qkv + base + (size_t)r * (3 * D_) + hcol;
#pragma unroll
    for (int d0 = 0; d0 < 8; ++d0) {
      union { uint4 u; __hip_bfloat16 h[8]; } uu;
      uu.u = *(const uint4*)(qp + d0 * 8);
#pragma unroll
      for (int j = 0; j < 8; ++j) qa[d0 * 8 + j] = __bfloat162float(uu.h[j]);
    }
  }
  // ---- scores = q.K^T / 8 ----
  for (int t = 0; t < 2; ++t) {
    __syncthreads();
    for (int idx = tid; idx < 400; idx += 128) {
      int j = idx >> 3, d8 = idx & 7;
      union { uint4 u; __hip_bfloat16 h[8]; } uu;
      uu.u = *(const uint4*)(qkv + base + (size_t)(t * 50 + j) * (3 * D_) + D_ + hcol + d8 * 8);
#pragma unroll
      for (int e = 0; e < 8; ++e) KV[j][d8 * 8 + e] = __bfloat162float(uu.h[e]);
    }
    __syncthreads();
    if (r < 100) {
      for (int j = 0; j < 50; ++j) {
        float s = 0.f;
#pragma unroll
        for (int d0 = 0; d0 < 16; ++d0) {
          float4 kv = *(const float4*)&KV[j][d0 * 4];
          s += qa[d0 * 4 + 0] * kv.x + qa[d0 * 4 + 1] * kv.y +
               qa[d0 * 4 + 2] * kv.z + qa[d0 * 4 + 3] * kv.w;
        }
        Sc[r][t * 50 + j] = s * 0.125f;
      }
    }
  }
  // ---- softmax along own row ----
  float inv_sum = 0.f;
  if (r < 100) {
    float mx = -1e30f;
    for (int j = 0; j < 100; ++j) mx = fmaxf(mx, Sc[r][j]);
    float sum = 0.f;
    for (int j = 0; j < 100; ++j) {
      float e = expf(Sc[r][j] - mx);
      Sc[r][j] = e;
      sum += e;
    }
    inv_sum = 1.0f / sum;
  }
  // ---- ctx = P.V ----
  float ca[64];
#pragma unroll
  for (int d = 0; d < 64; ++d) ca[d] = 0.f;
  for (int t = 0; t < 2; ++t) {
    __syncthreads();
    for (int idx = tid; idx < 400; idx += 128) {
      int j = idx >> 3, d8 = idx & 7;
      union { uint4 u; __hip_bfloat16 h[8]; } uu;
      uu.u = *(const uint4*)(qkv + base + (size_t)(t * 50 + j) * (3 * D_) + 2 * D_ + hcol + d8 * 8);
#pragma unroll
      for (int e = 0; e < 8; ++e) KV[j][d8 * 8 + e] = __bfloat162float(uu.h[e]);
    }
    __syncthreads();
    if (r < 100) {
      for (int j = 0; j < 50; ++j) {
        float p = Sc[r][t * 50 + j];
#pragma unroll
        for (int d0 = 0; d0 < 16; ++d0) {
          float4 kv = *(const float4*)&KV[j][d0 * 4];
          ca[d0 * 4 + 0] += p * kv.x;
          ca[d0 * 4 + 1] += p * kv.y;
          ca[d0 * 4 + 2] += p * kv.z;
          ca[d0 * 4 + 3] += p * kv.w;
        }
      }
    }
  }
  if (r < 100) {
    __hip_bfloat16* cp = ctx + ((size_t)b * S_ + r) * D_ + hcol;
#pragma unroll
    for (int d = 0; d < 64; ++d) cp[d] = __float2bfloat16(ca[d] * inv_sum);
  }
}

// ------------------------------------------------------------------
// h = LN(h + res) * scale + bias   (fp32) and bf16 copy
// ------------------------------------------------------------------
__device__ float block_sum_1024(float v) {
#pragma unroll
  for (int off = 32; off > 0; off >>= 1) v += __shfl_down(v, off);
  __shared__ float sm[4];
  __syncthreads();
  int lane = threadIdx.x & 63, wv = threadIdx.x >> 6;
  if (lane == 0) sm[wv] = v;
  __syncthreads();
  return sm[0] + sm[1] + sm[2] + sm[3];
}

__global__ __launch_bounds__(256) void add_ln_kernel(float* __restrict__ h,
    const float* __restrict__ res, const float* __restrict__ scale,
    const float* __restrict__ bias, __hip_bfloat16* __restrict__ hb) {
  size_t base = (size_t)blockIdx.x * D_;
  int tid = threadIdx.x;
  float x[4];
  float s = 0.f;
#pragma unroll
  for (int i = 0; i < 4; ++i) {
    x[i] = h[base + tid + i * 256] + res[base + tid + i * 256];
    s += x[i];
  }
  float mu = block_sum_1024(s) * (1.0f / 1024.0f);
  float v = 0.f;
#pragma unroll
  for (int i = 0; i < 4; ++i) {
    float d = x[i] - mu;
    v += d * d;
  }
  float var = block_sum_1024(v) * (1.0f / 1024.0f);
  float rs = rsqrtf(var + 1e-5f);
#pragma unroll
  for (int i = 0; i < 4; ++i) {
    int d = tid + i * 256;
    float o = (x[i] - mu) * rs * scale[d] + bias[d];
    h[base + d] = o;
    hb[base + d] = __float2bfloat16(o);
  }
}

// ------------------------------------------------------------------
extern "C" void kernel_launch(void* const* d_in, const int* in_sizes, int n_in,
                              void* d_out, int out_size, void* d_ws, size_t ws_size,
                              hipStream_t stream) {
  const int* x       = (const int*)d_in[0];
  const float* emb   = (const float*)d_in[1];
  const float* pos   = (const float*)d_in[2];
  const float* qkv_w = (const float*)d_in[3];
  const float* qkv_b = (const float*)d_in[4];
  const float* out_w = (const float*)d_in[5];
  const float* out_b = (const float*)d_in[6];
  const float* ln1_s = (const float*)d_in[7];
  const float* ln1_b = (const float*)d_in[8];
  const float* ff1_w = (const float*)d_in[9];
  const float* ff1_b = (const float*)d_in[10];
  const float* ff2_w = (const float*)d_in[11];
  const float* ff2_b = (const float*)d_in[12];
  const float* ln2_s = (const float*)d_in[13];
  const float* ln2_b = (const float*)d_in[14];
  const float* dec_w = (const float*)d_in[15];
  const float* dec_b = (const float*)d_in[16];
  float* out = (float*)d_out;

  char* ws = (char*)d_ws;
  size_t off = 0;
  auto alloc = [&](size_t bytes) { void* p = ws + off; off += (bytes + 255) & ~(size_t)255; return p; };
  double* gsum            = (double*)alloc(256);
  float* h                = (float*)alloc((size_t)3200 * 1024 * 4);
  __hip_bfloat16* h_bf    = (__hip_bfloat16*)alloc((size_t)3200 * 1024 * 2);
  float* tmp              = (float*)alloc((size_t)3200 * 1024 * 4);
  __hip_bfloat16* ctx_bf  = (__hip_bfloat16*)alloc((size_t)3200 * 1024 * 2);
  __hip_bfloat16* big_bf  = (__hip_bfloat16*)alloc((size_t)3200 * 4096 * 2);  // qkv out / ff1 out
  __hip_bfloat16* weff    = (__hip_bfloat16*)alloc((size_t)32000 * 1024 * 2);
  __hip_bfloat16* qkvw_bf = (__hip_bfloat16*)alloc((size_t)2 * 3072 * 1024 * 2);
  __hip_bfloat16* outw_bf = (__hip_bfloat16*)alloc((size_t)2 * 1024 * 1024 * 2);
  __hip_bfloat16* ff1w_bf = (__hip_bfloat16*)alloc((size_t)2 * 4096 * 1024 * 2);
  __hip_bfloat16* ff2w_bf = (__hip_bfloat16*)alloc((size_t)2 * 1024 * 4096 * 2);

  hipMemsetAsync(gsum, 0, 256, stream);  // ws not re-poisoned between replays
  absmean_kernel<<<2048, 256, 0, stream>>>(dec_w, gsum);
  quantize_kernel<<<4096, 256, 0, stream>>>(dec_w, gsum, weff);
  cast_kernel<<<2048, 256, 0, stream>>>(qkv_w, qkvw_bf, (long long)2 * 3072 * 1024 / 4);
  cast_kernel<<<2048, 256, 0, stream>>>(out_w, outw_bf, (long long)2 * 1024 * 1024 / 4);
  cast_kernel<<<2048, 256, 0, stream>>>(ff1_w, ff1w_bf, (long long)2 * 4096 * 1024 / 4);
  cast_kernel<<<2048, 256, 0, stream>>>(ff2_w, ff2w_bf, (long long)2 * 1024 * 4096 / 4);
  embed_kernel<<<3200, 256, 0, stream>>>(x, emb, pos, h, h_bf);

  const int M = 3200;
  for (int l = 0; l < 2; ++l) {
    gemm_bf<0, 1><<<dim3(M / 128, 3072 / 128), 256, 0, stream>>>(
        h_bf, qkvw_bf + (size_t)l * 3072 * 1024, qkv_b + l * 3072, big_bf, M, 3072, 1024);
    attn_kernel<<<512, 128, 0, stream>>>(big_bf, ctx_bf);
    gemm_bf<0, 0><<<dim3(M / 128, 1024 / 128), 256, 0, stream>>>(
        ctx_bf, outw_bf + (size_t)l * 1024 * 1024, out_b + l * 1024, tmp, M, 1024, 1024);
    add_ln_kernel<<<M, 256, 0, stream>>>(h, tmp, ln1_s + l * 1024, ln1_b + l * 1024, h_bf);
    gemm_bf<1, 1><<<dim3(M / 128, 4096 / 128), 256, 0, stream>>>(
        h_bf, ff1w_bf + (size_t)l * 4096 * 1024, ff1_b + l * 4096, big_bf, M, 4096, 1024);
    gemm_bf<0, 0><<<dim3(M / 128, 1024 / 128), 256, 0, stream>>>(
        big_bf, ff2w_bf + (size_t)l * 1024 * 4096, ff2_b + l * 1024, tmp, M, 1024, 4096);
    add_ln_kernel<<<M, 256, 0, stream>>>(h, tmp, ln2_s + l * 1024, ln2_b + l * 1024, h_bf);
  }
  // ternary decoder: out = h @ w_eff^T + dec_b
  gemm_bf<0, 0><<<dim3(M / 128, 32000 / 128), 256, 0, stream>>>(
      h_bf, weff, dec_b, out, M, 32000, 1024);
}

// Round 5
// 981.137 us; speedup vs baseline: 5.6155x; 1.1316x over previous
//
#include <hip/hip_runtime.h>
#include <hip/hip_bf16.h>
#include <math.h>

#define B_ 32
#define S_ 100
#define D_ 1024
#define H_ 16
#define L_ 2
#define V_ 32000
#define DF_ 4096
#define HD_ 64
#define MPAD 3328   // 3200 padded to 13*256

typedef __bf16 bf16x8 __attribute__((ext_vector_type(8)));
typedef float f32x4 __attribute__((ext_vector_type(4)));

__device__ __forceinline__ void async_copy16(const void* g, void* l) {
  __builtin_amdgcn_global_load_lds((const __attribute__((address_space(1))) void*)g,
                                   (__attribute__((address_space(3))) void*)l, 16, 0, 0);
}

// ------------------------------------------------------------------
// g = mean(|dec_w|) in float64 (order-insensitive to ~1e-13 relative)
// ------------------------------------------------------------------
__global__ void absmean_kernel(const float* __restrict__ w, double* __restrict__ out) {
  const long long n4 = (long long)V_ * D_ / 4;
  double s = 0.0;
  long long stride = (long long)gridDim.x * blockDim.x;
  for (long long i = (long long)blockIdx.x * blockDim.x + threadIdx.x; i < n4; i += stride) {
    float4 v = ((const float4*)w)[i];
    s += (double)fabsf(v.x) + (double)fabsf(v.y) + (double)fabsf(v.z) + (double)fabsf(v.w);
  }
#pragma unroll
  for (int off = 32; off > 0; off >>= 1) s += __shfl_down(s, off);
  __shared__ double sm[4];
  int lane = threadIdx.x & 63, wv = threadIdx.x >> 6;
  if (lane == 0) sm[wv] = s;
  __syncthreads();
  if (threadIdx.x == 0) atomicAdd(out, sm[0] + sm[1] + sm[2] + sm[3]);
}

// packed effective ternary weight as bf16: {q==0:+1, q==+1:-1, q==-1:0}
__global__ void quantize_kernel(const float* __restrict__ w, const double* __restrict__ gsum,
                                __hip_bfloat16* __restrict__ q) {
  const long long n4 = (long long)V_ * D_ / 4;
  double g = (*gsum) / ((double)V_ * D_) + 1e-6;
  long long stride = (long long)gridDim.x * blockDim.x;
  for (long long i = (long long)blockIdx.x * blockDim.x + threadIdx.x; i < n4; i += stride) {
    float4 v = ((const float4*)w)[i];
    union { __hip_bfloat16 h[4]; uint2 u; } o;
    float vv[4] = {v.x, v.y, v.z, v.w};
#pragma unroll
    for (int j = 0; j < 4; ++j) {
      double r = rint((double)vv[j] / g);  // half-to-even, matches np.round
      r = fmin(1.0, fmax(-1.0, r));
      float w_eff = (r == 0.0) ? 1.0f : ((r == 1.0) ? -1.0f : 0.0f);
      o.h[j] = __float2bfloat16(w_eff);  // exact
    }
    ((uint2*)q)[i] = o.u;
  }
}

// fp32 -> bf16 bulk cast (n multiple of 4)
__global__ void cast_kernel(const float* __restrict__ in, __hip_bfloat16* __restrict__ out,
                            long long n4) {
  long long stride = (long long)gridDim.x * blockDim.x;
  for (long long i = (long long)blockIdx.x * blockDim.x + threadIdx.x; i < n4; i += stride) {
    float4 v = ((const float4*)in)[i];
    union { __hip_bfloat16 h[4]; uint2 u; } o;
    o.h[0] = __float2bfloat16(v.x);
    o.h[1] = __float2bfloat16(v.y);
    o.h[2] = __float2bfloat16(v.z);
    o.h[3] = __float2bfloat16(v.w);
    ((uint2*)out)[i] = o.u;
  }
}

// ------------------------------------------------------------------
// h[b,s,:] = emb[x[b,s],:] + pos[s,:]  -> fp32 h and bf16 h_bf
// ------------------------------------------------------------------
__global__ __launch_bounds__(256) void embed_kernel(const int* __restrict__ x,
    const float* __restrict__ emb, const float* __restrict__ pos,
    float* __restrict__ h, __hip_bfloat16* __restrict__ hb) {
  int row = blockIdx.x;  // b*S + s
  int s = row % S_;
  int tok = x[row];
  size_t eb = (size_t)tok * D_, pb = (size_t)s * D_, hb0 = (size_t)row * D_;
#pragma unroll
  for (int i = 0; i < 4; ++i) {
    int d = threadIdx.x + i * 256;
    float v = emb[eb + d] + pos[pb + d];
    h[hb0 + d] = v;
    hb[hb0 + d] = __float2bfloat16(v);
  }
}

__device__ __forceinline__ float gelu_exact(float v) {
  return 0.5f * v * (1.0f + erff(v * 0.70710678118654752f));
}

// ------------------------------------------------------------------
// m97-structure bf16 MFMA GEMM, 128x128 tile, BK=32, 4 waves.
// Split-K via blockIdx.z: z picks K-chunk [z*K, (z+1)*K) of lda-strided
// rows; z==0 writes C (with bias), z==1 writes C2 (no bias). Partials
// are summed in add_ln. XCD-bijective swizzle on (x,y).
// ------------------------------------------------------------------
template <int ACT, int OUTBF>
__global__ __launch_bounds__(256) void gemm_bf(const __hip_bfloat16* __restrict__ A,
    const __hip_bfloat16* __restrict__ Bm, const float* __restrict__ bias,
    void* __restrict__ C, void* __restrict__ C2, int M, int N, int K, int lda, int ldb) {
  __shared__ __bf16 As[128 * 32];
  __shared__ __bf16 Bs[128 * 32];
  int tid = threadIdx.x;
  int lane = tid & 63, wid = tid >> 6;
  int wr = wid >> 1, wc = wid & 1;  // wave -> 64x64 quadrant
  int z = blockIdx.z;

  // ---- bijective XCD swizzle (T1 / m204) ----
  int nwg = gridDim.x * gridDim.y;
  int orig = blockIdx.y * gridDim.x + blockIdx.x;
  int q = nwg >> 3, r = nwg & 7;
  int xcd = orig & 7, local = orig >> 3;
  int wgid = (xcd < r ? xcd * (q + 1) : r * (q + 1) + (xcd - r) * q) + local;
  int row0 = (wgid % gridDim.x) * 128;  // gridDim.x = M/128 (M fastest)
  int col0 = (wgid / gridDim.x) * 128;

  const __hip_bfloat16* Az = A + (size_t)z * K;
  const __hip_bfloat16* Bz = Bm + (size_t)z * K;
  int j0 = wid * 2;
  const __hip_bfloat16* Ag0 = Az + (size_t)(row0 + j0 * 16 + (lane >> 2)) * lda + (lane & 3) * 8;
  const __hip_bfloat16* Ag1 = Az + (size_t)(row0 + (j0 + 1) * 16 + (lane >> 2)) * lda + (lane & 3) * 8;
  const __hip_bfloat16* Bg0 = Bz + (size_t)(col0 + j0 * 16 + (lane >> 2)) * ldb + (lane & 3) * 8;
  const __hip_bfloat16* Bg1 = Bz + (size_t)(col0 + (j0 + 1) * 16 + (lane >> 2)) * ldb + (lane & 3) * 8;
  __bf16* Al0 = As + j0 * 512;
  __bf16* Al1 = As + (j0 + 1) * 512;
  __bf16* Bl0 = Bs + j0 * 512;
  __bf16* Bl1 = Bs + (j0 + 1) * 512;

  float bias_v[4];
#pragma unroll
  for (int ni = 0; ni < 4; ++ni)
    bias_v[ni] = (z == 0) ? bias[col0 + wc * 64 + ni * 16 + (lane & 15)] : 0.f;

  f32x4 acc[4][4];
#pragma unroll
  for (int mi = 0; mi < 4; ++mi)
#pragma unroll
    for (int ni = 0; ni < 4; ++ni) acc[mi][ni] = (f32x4){0.f, 0.f, 0.f, 0.f};

  const bf16x8* Asv = reinterpret_cast<const bf16x8*>(As);
  const bf16x8* Bsv = reinterpret_cast<const bf16x8*>(Bs);
  int afr = (wr * 64 + (lane & 15)) * 4 + (lane >> 4);  // in 8-elem units
  int bfr = (wc * 64 + (lane & 15)) * 4 + (lane >> 4);

  for (int k0 = 0; k0 < K; k0 += 32) {
    async_copy16(Ag0, Al0);
    async_copy16(Ag1, Al1);
    async_copy16(Bg0, Bl0);
    async_copy16(Bg1, Bl1);
    Ag0 += 32; Ag1 += 32; Bg0 += 32; Bg1 += 32;
    __syncthreads();  // drains vmcnt: LDS tile visible to all waves
    bf16x8 af[4], bf[4];
#pragma unroll
    for (int mi = 0; mi < 4; ++mi) af[mi] = Asv[afr + mi * 64];
#pragma unroll
    for (int ni = 0; ni < 4; ++ni) bf[ni] = Bsv[bfr + ni * 64];
#pragma unroll
    for (int mi = 0; mi < 4; ++mi)
#pragma unroll
      for (int ni = 0; ni < 4; ++ni)
        acc[mi][ni] = __builtin_amdgcn_mfma_f32_16x16x32_bf16(af[mi], bf[ni], acc[mi][ni], 0, 0, 0);
    __syncthreads();  // compute done before next-tile overwrite
  }

  float* Cf = (float*)((z == 0) ? C : C2);
  __hip_bfloat16* Cb = (__hip_bfloat16*)C;
#pragma unroll
  for (int mi = 0; mi < 4; ++mi) {
#pragma unroll
    for (int r2 = 0; r2 < 4; ++r2) {
      size_t m = row0 + wr * 64 + mi * 16 + (lane >> 4) * 4 + r2;
#pragma unroll
      for (int ni = 0; ni < 4; ++ni) {
        size_t n = col0 + wc * 64 + ni * 16 + (lane & 15);
        float v = acc[mi][ni][r2] + bias_v[ni];
        if (ACT == 1) v = gelu_exact(v);
        if (OUTBF) Cb[m * N + n] = __float2bfloat16(v);
        else       Cf[m * N + n] = v;
      }
    }
  }
}

// ------------------------------------------------------------------
// 8-phase 256x256 GEMM (T2+T3+T4+T5), BK=64, 512 threads = 8 waves
// (2M x 4N), per-wave 128x64 output. LDS 128 KiB (2 buf x 2 half x
// [kk][128 rows][32 cols] x A,B). Raw s_barrier + counted vmcnt(4);
// st-16x32-style XOR swizzle via pre-swizzled global source.
// Stage order per tile T: ph0 (T+1)A1, ph1 (T+1)B1, ph2 (T+2)B0,
// ph3 (T+2)A0  [each issued only after its LDS region's last reader
// phase has drained]. C-store guarded m < Mreal (A padded to MPAD).
// ------------------------------------------------------------------
__global__ __launch_bounds__(512, 1) void gemm256_dec(
    const __hip_bfloat16* __restrict__ A, const __hip_bfloat16* __restrict__ Bm,
    const float* __restrict__ bias, float* __restrict__ C,
    int Mreal, int N, int K) {
  extern __shared__ char lds[];
  char* ldsA = lds;            // 65536 B
  char* ldsB = lds + 65536;    // 65536 B
  const int t = threadIdx.x;
  const int lane = t & 63, wid = t >> 6;
  const int wm = wid >> 2, wn = wid & 3;
  const int NT = K >> 6;

  // bijective XCD swizzle, M fastest
  int nwg = gridDim.x * gridDim.y;
  int orig = blockIdx.y * gridDim.x + blockIdx.x;
  int q = nwg >> 3, r = nwg & 7;
  int xcd = orig & 7, local = orig >> 3;
  int wgid = (xcd < r ? xcd * (q + 1) : r * (q + 1) + (xcd - r) * q) + local;
  int row0 = (wgid % gridDim.x) * 256;
  int col0 = (wgid / gridDim.x) * 256;

  // staging source geometry: thread t stages rows t>>2 of a half,
  // k-cols pre-swizzled so linear LDS dest + swizzled read match.
  const int rs = t >> 2;                                           // 0..127
  const int kc = ((((t & 3) << 4) ^ (((t >> 5) & 1) << 5)) >> 1);  // 0..31
  const __hip_bfloat16* Asrc = A + (size_t)(row0 + rs) * K + kc;
  const __hip_bfloat16* Bsrc = Bm + (size_t)(col0 + rs) * K + kc;

#define STAGE_A(b, h, tgt) do { \
    const __hip_bfloat16* _s = Asrc + (size_t)(h) * 128 * K + (tgt) * 64; \
    char* _d = ldsA + (b) * 32768 + (h) * 16384 + t * 16; \
    async_copy16(_s, _d); async_copy16(_s + 32, _d + 8192); } while (0)
#define STAGE_B(b, h, tgt) do { \
    const __hip_bfloat16* _s = Bsrc + (size_t)(h) * 128 * K + (tgt) * 64; \
    char* _d = ldsB + (b) * 32768 + (h) * 16384 + t * 16; \
    async_copy16(_s, _d); async_copy16(_s + 32, _d + 8192); } while (0)
#define SB() __builtin_amdgcn_sched_barrier(0)
#define BAR() __builtin_amdgcn_s_barrier()

  // fragment read offset within a half: row=(lane&15)+mi*16, kchunk=(lane>>4)*16B,
  // XOR bit5 keyed on row bit3 (= lane bit3, mi-independent)
  const int sb5 = ((lane >> 3) & 1) << 5;
  const int laneoff = ((lane & 15) << 6) + (((lane >> 4) << 4) ^ sb5);

  f32x4 acc[8][4];
#pragma unroll
  for (int i = 0; i < 8; ++i)
#pragma unroll
    for (int j = 0; j < 4; ++j) acc[i][j] = (f32x4){0.f, 0.f, 0.f, 0.f};

  // prologue: tile0 {A0,B0,A1,B1}, tile1 {B0,A0}; need tile0 landed -> vmcnt(4)
  STAGE_A(0, 0, 0); STAGE_B(0, 0, 0); STAGE_A(0, 1, 0); STAGE_B(0, 1, 0);
  STAGE_B(1, 0, 1); STAGE_A(1, 0, 1);
  asm volatile("s_waitcnt vmcnt(4)" ::: "memory");
  SB(); BAR(); SB();

  bf16x8 a[4][2], b[4][2];
  for (int T = 0; T < NT; ++T) {
    const int bs = T & 1;
    const char* Aw = ldsA + bs * 32768 + wm * 16384 + laneoff;
    const char* Bw = ldsB + bs * 32768 + (wn >> 1) * 16384 + (wn & 1) * 4096 + laneoff;
    // ---------- phase 0: read A[mi0-3],B[ni0-1]; stage (T+1)A1 ----------
#pragma unroll
    for (int mi = 0; mi < 4; ++mi)
#pragma unroll
      for (int kk = 0; kk < 2; ++kk)
        a[mi][kk] = *(const bf16x8*)(Aw + mi * 1024 + kk * 8192);
#pragma unroll
    for (int ni = 0; ni < 2; ++ni)
#pragma unroll
      for (int kk = 0; kk < 2; ++kk)
        b[ni][kk] = *(const bf16x8*)(Bw + ni * 1024 + kk * 8192);
    if (T + 1 < NT) STAGE_A(bs ^ 1, 1, T + 1);
    SB(); BAR(); SB();
    __builtin_amdgcn_s_setprio(1);
#pragma unroll
    for (int mi = 0; mi < 4; ++mi)
#pragma unroll
      for (int ni = 0; ni < 2; ++ni)
#pragma unroll
        for (int kk = 0; kk < 2; ++kk)
          acc[mi][ni] = __builtin_amdgcn_mfma_f32_16x16x32_bf16(a[mi][kk], b[ni][kk], acc[mi][ni], 0, 0, 0);
    __builtin_amdgcn_s_setprio(0);
    SB(); BAR(); SB();
    // ---------- phase 1: read B[ni2-3]; stage (T+1)B1 ----------
#pragma unroll
    for (int ni = 2; ni < 4; ++ni)
#pragma unroll
      for (int kk = 0; kk < 2; ++kk)
        b[ni][kk] = *(const bf16x8*)(Bw + ni * 1024 + kk * 8192);
    if (T + 1 < NT) STAGE_B(bs ^ 1, 1, T + 1);
    SB(); BAR(); SB();
    __builtin_amdgcn_s_setprio(1);
#pragma unroll
    for (int mi = 0; mi < 4; ++mi)
#pragma unroll
      for (int ni = 2; ni < 4; ++ni)
#pragma unroll
        for (int kk = 0; kk < 2; ++kk)
          acc[mi][ni] = __builtin_amdgcn_mfma_f32_16x16x32_bf16(a[mi][kk], b[ni][kk], acc[mi][ni], 0, 0, 0);
    __builtin_amdgcn_s_setprio(0);
    SB(); BAR(); SB();
    // ---------- phase 2: read A[mi4-7]; stage (T+2)B0 ----------
#pragma unroll
    for (int mi = 0; mi < 4; ++mi)
#pragma unroll
      for (int kk = 0; kk < 2; ++kk)
        a[mi][kk] = *(const bf16x8*)(Aw + (mi + 4) * 1024 + kk * 8192);
    if (T + 2 < NT) STAGE_B(bs, 0, T + 2);
    SB(); BAR(); SB();
    __builtin_amdgcn_s_setprio(1);
#pragma unroll
    for (int mi = 0; mi < 4; ++mi)
#pragma unroll
      for (int ni = 0; ni < 2; ++ni)
#pragma unroll
        for (int kk = 0; kk < 2; ++kk)
          acc[mi + 4][ni] = __builtin_amdgcn_mfma_f32_16x16x32_bf16(a[mi][kk], b[ni][kk], acc[mi + 4][ni], 0, 0, 0);
    __builtin_amdgcn_s_setprio(0);
    SB(); BAR(); SB();
    // ---------- phase 3: stage (T+2)A0; counted vmcnt; MFMA ----------
    if (T + 2 < NT) STAGE_A(bs, 0, T + 2);
    if (T < NT - 2) { asm volatile("s_waitcnt vmcnt(4)" ::: "memory"); }
    else            { asm volatile("s_waitcnt vmcnt(0)" ::: "memory"); }
    SB(); BAR(); SB();
    __builtin_amdgcn_s_setprio(1);
#pragma unroll
    for (int mi = 0; mi < 4; ++mi)
#pragma unroll
      for (int ni = 2; ni < 4; ++ni)
#pragma unroll
        for (int kk = 0; kk < 2; ++kk)
          acc[mi + 4][ni] = __builtin_amdgcn_mfma_f32_16x16x32_bf16(a[mi][kk], b[ni][kk], acc[mi + 4][ni], 0, 0, 0);
    __builtin_amdgcn_s_setprio(0);
    SB(); BAR(); SB();
  }
#undef STAGE_A
#undef STAGE_B
#undef SB
#undef BAR

  // epilogue
  float bias_v[4];
#pragma unroll
  for (int ni = 0; ni < 4; ++ni)
    bias_v[ni] = bias[col0 + wn * 64 + ni * 16 + (lane & 15)];
#pragma unroll
  for (int mi = 0; mi < 8; ++mi) {
#pragma unroll
    for (int r2 = 0; r2 < 4; ++r2) {
      int m = row0 + wm * 128 + mi * 16 + (lane >> 4) * 4 + r2;
      if (m < Mreal) {
#pragma unroll
        for (int ni = 0; ni < 4; ++ni) {
          int n = col0 + wn * 64 + ni * 16 + (lane & 15);
          C[(size_t)m * N + n] = acc[mi][ni][r2] + bias_v[ni];
        }
      }
    }
  }
}

// ------------------------------------------------------------------
// Fused attention per (b,h): bf16 in/out, fp32 compute. S=100, hd=64.
// ------------------------------------------------------------------
__global__ __launch_bounds__(128) void attn_kernel(const __hip_bfloat16* __restrict__ qkv,
                                                   __hip_bfloat16* __restrict__ ctx) {
  __shared__ float KV[50][64];
  __shared__ float Sc[100][100];
  int bh = blockIdx.x;  // b*H + h
  int b = bh >> 4, hh = bh & 15;
  int tid = threadIdx.x;
  size_t base = (size_t)b * S_ * (3 * D_);
  int hcol = hh * HD_;
  int r = tid;

  float qa[64];
  if (r < 100) {
    const __hip_bfloat16* qp = qkv + base + (size_t)r * (3 * D_) + hcol;
#pragma unroll
    for (int d0 = 0; d0 < 8; ++d0) {
      union { uint4 u; __hip_bfloat16 h[8]; } uu;
      uu.u = *(const uint4*)(qp + d0 * 8);
#pragma unroll
      for (int j = 0; j < 8; ++j) qa[d0 * 8 + j] = __bfloat162float(uu.h[j]);
    }
  }
  for (int tt = 0; tt < 2; ++tt) {
    __syncthreads();
    for (int idx = tid; idx < 400; idx += 128) {
      int j = idx >> 3, d8 = idx & 7;
      union { uint4 u; __hip_bfloat16 h[8]; } uu;
      uu.u = *(const uint4*)(qkv + base + (size_t)(tt * 50 + j) * (3 * D_) + D_ + hcol + d8 * 8);
#pragma unroll
      for (int e = 0; e < 8; ++e) KV[j][d8 * 8 + e] = __bfloat162float(uu.h[e]);
    }
    __syncthreads();
    if (r < 100) {
      for (int j = 0; j < 50; ++j) {
        float s = 0.f;
#pragma unroll
        for (int d0 = 0; d0 < 16; ++d0) {
          float4 kv = *(const float4*)&KV[j][d0 * 4];
          s += qa[d0 * 4 + 0] * kv.x + qa[d0 * 4 + 1] * kv.y +
               qa[d0 * 4 + 2] * kv.z + qa[d0 * 4 + 3] * kv.w;
        }
        Sc[r][tt * 50 + j] = s * 0.125f;
      }
    }
  }
  float inv_sum = 0.f;
  if (r < 100) {
    float mx = -1e30f;
    for (int j = 0; j < 100; ++j) mx = fmaxf(mx, Sc[r][j]);
    float sum = 0.f;
    for (int j = 0; j < 100; ++j) {
      float e = expf(Sc[r][j] - mx);
      Sc[r][j] = e;
      sum += e;
    }
    inv_sum = 1.0f / sum;
  }
  float ca[64];
#pragma unroll
  for (int d = 0; d < 64; ++d) ca[d] = 0.f;
  for (int tt = 0; tt < 2; ++tt) {
    __syncthreads();
    for (int idx = tid; idx < 400; idx += 128) {
      int j = idx >> 3, d8 = idx & 7;
      union { uint4 u; __hip_bfloat16 h[8]; } uu;
      uu.u = *(const uint4*)(qkv + base + (size_t)(tt * 50 + j) * (3 * D_) + 2 * D_ + hcol + d8 * 8);
#pragma unroll
      for (int e = 0; e < 8; ++e) KV[j][d8 * 8 + e] = __bfloat162float(uu.h[e]);
    }
    __syncthreads();
    if (r < 100) {
      for (int j = 0; j < 50; ++j) {
        float p = Sc[r][tt * 50 + j];
#pragma unroll
        for (int d0 = 0; d0 < 16; ++d0) {
          float4 kv = *(const float4*)&KV[j][d0 * 4];
          ca[d0 * 4 + 0] += p * kv.x;
          ca[d0 * 4 + 1] += p * kv.y;
          ca[d0 * 4 + 2] += p * kv.z;
          ca[d0 * 4 + 3] += p * kv.w;
        }
      }
    }
  }
  if (r < 100) {
    __hip_bfloat16* cp = ctx + ((size_t)b * S_ + r) * D_ + hcol;
#pragma unroll
    for (int d = 0; d < 64; ++d) cp[d] = __float2bfloat16(ca[d] * inv_sum);
  }
}

// ------------------------------------------------------------------
// h = LN(h + res [+ res2]) * scale + bias   (fp32) and bf16 copy
// ------------------------------------------------------------------
__device__ float block_sum_1024(float v) {
#pragma unroll
  for (int off = 32; off > 0; off >>= 1) v += __shfl_down(v, off);
  __shared__ float sm[4];
  __syncthreads();
  int lane = threadIdx.x & 63, wv = threadIdx.x >> 6;
  if (lane == 0) sm[wv] = v;
  __syncthreads();
  return sm[0] + sm[1] + sm[2] + sm[3];
}

__global__ __launch_bounds__(256) void add_ln_kernel(float* __restrict__ h,
    const float* __restrict__ res, const float* __restrict__ res2,
    const float* __restrict__ scale, const float* __restrict__ bias,
    __hip_bfloat16* __restrict__ hb) {
  size_t base = (size_t)blockIdx.x * D_;
  int tid = threadIdx.x;
  float x[4];
  float s = 0.f;
#pragma unroll
  for (int i = 0; i < 4; ++i) {
    size_t ix = base + tid + i * 256;
    float v = h[ix] + res[ix];
    if (res2) v += res2[ix];
    x[i] = v;
    s += v;
  }
  float mu = block_sum_1024(s) * (1.0f / 1024.0f);
  float v = 0.f;
#pragma unroll
  for (int i = 0; i < 4; ++i) {
    float d = x[i] - mu;
    v += d * d;
  }
  float var = block_sum_1024(v) * (1.0f / 1024.0f);
  float rs = rsqrtf(var + 1e-5f);
#pragma unroll
  for (int i = 0; i < 4; ++i) {
    int d = tid + i * 256;
    float o = (x[i] - mu) * rs * scale[d] + bias[d];
    h[base + d] = o;
    hb[base + d] = __float2bfloat16(o);
  }
}

// ------------------------------------------------------------------
extern "C" void kernel_launch(void* const* d_in, const int* in_sizes, int n_in,
                              void* d_out, int out_size, void* d_ws, size_t ws_size,
                              hipStream_t stream) {
  const int* x       = (const int*)d_in[0];
  const float* emb   = (const float*)d_in[1];
  const float* pos   = (const float*)d_in[2];
  const float* qkv_w = (const float*)d_in[3];
  const float* qkv_b = (const float*)d_in[4];
  const float* out_w = (const float*)d_in[5];
  const float* out_b = (const float*)d_in[6];
  const float* ln1_s = (const float*)d_in[7];
  const float* ln1_b = (const float*)d_in[8];
  const float* ff1_w = (const float*)d_in[9];
  const float* ff1_b = (const float*)d_in[10];
  const float* ff2_w = (const float*)d_in[11];
  const float* ff2_b = (const float*)d_in[12];
  const float* ln2_s = (const float*)d_in[13];
  const float* ln2_b = (const float*)d_in[14];
  const float* dec_w = (const float*)d_in[15];
  const float* dec_b = (const float*)d_in[16];
  float* out = (float*)d_out;

  char* ws = (char*)d_ws;
  size_t off = 0;
  auto alloc = [&](size_t bytes) { void* p = ws + off; off += (bytes + 255) & ~(size_t)255; return p; };
  double* gsum            = (double*)alloc(256);
  float* h                = (float*)alloc((size_t)3200 * 1024 * 4);
  __hip_bfloat16* h_bf    = (__hip_bfloat16*)alloc((size_t)MPAD * 1024 * 2);  // padded for 256-tiles
  float* tmp              = (float*)alloc((size_t)3200 * 1024 * 4);
  float* tmp2             = (float*)alloc((size_t)3200 * 1024 * 4);
  __hip_bfloat16* ctx_bf  = (__hip_bfloat16*)alloc((size_t)3200 * 1024 * 2);
  __hip_bfloat16* big_bf  = (__hip_bfloat16*)alloc((size_t)3200 * 4096 * 2);  // qkv out / ff1 out
  __hip_bfloat16* weff    = (__hip_bfloat16*)alloc((size_t)32000 * 1024 * 2);
  __hip_bfloat16* qkvw_bf = (__hip_bfloat16*)alloc((size_t)2 * 3072 * 1024 * 2);
  __hip_bfloat16* outw_bf = (__hip_bfloat16*)alloc((size_t)2 * 1024 * 1024 * 2);
  __hip_bfloat16* ff1w_bf = (__hip_bfloat16*)alloc((size_t)2 * 4096 * 1024 * 2);
  __hip_bfloat16* ff2w_bf = (__hip_bfloat16*)alloc((size_t)2 * 1024 * 4096 * 2);

  hipMemsetAsync(gsum, 0, 256, stream);  // ws not re-poisoned between replays
  absmean_kernel<<<2048, 256, 0, stream>>>(dec_w, gsum);
  quantize_kernel<<<4096, 256, 0, stream>>>(dec_w, gsum, weff);
  cast_kernel<<<2048, 256, 0, stream>>>(qkv_w, qkvw_bf, (long long)2 * 3072 * 1024 / 4);
  cast_kernel<<<2048, 256, 0, stream>>>(out_w, outw_bf, (long long)2 * 1024 * 1024 / 4);
  cast_kernel<<<2048, 256, 0, stream>>>(ff1_w, ff1w_bf, (long long)2 * 4096 * 1024 / 4);
  cast_kernel<<<2048, 256, 0, stream>>>(ff2_w, ff2w_bf, (long long)2 * 1024 * 4096 / 4);
  embed_kernel<<<3200, 256, 0, stream>>>(x, emb, pos, h, h_bf);

  const int M = 3200;
  for (int l = 0; l < 2; ++l) {
    gemm_bf<0, 1><<<dim3(M / 128, 3072 / 128, 1), 256, 0, stream>>>(
        h_bf, qkvw_bf + (size_t)l * 3072 * 1024, qkv_b + l * 3072, big_bf, nullptr,
        M, 3072, 1024, 1024, 1024);
    attn_kernel<<<512, 128, 0, stream>>>(big_bf, ctx_bf);
    // out-proj: split-K2 (z=0 -> tmp + bias, z=1 -> tmp2)
    gemm_bf<0, 0><<<dim3(M / 128, 1024 / 128, 2), 256, 0, stream>>>(
        ctx_bf, outw_bf + (size_t)l * 1024 * 1024, out_b + l * 1024, tmp, tmp2,
        M, 1024, 512, 1024, 1024);
    add_ln_kernel<<<M, 256, 0, stream>>>(h, tmp, tmp2, ln1_s + l * 1024, ln1_b + l * 1024, h_bf);
    gemm_bf<1, 1><<<dim3(M / 128, 4096 / 128, 1), 256, 0, stream>>>(
        h_bf, ff1w_bf + (size_t)l * 4096 * 1024, ff1_b + l * 4096, big_bf, nullptr,
        M, 4096, 1024, 1024, 1024);
    // ff2: split-K2
    gemm_bf<0, 0><<<dim3(M / 128, 1024 / 128, 2), 256, 0, stream>>>(
        big_bf, ff2w_bf + (size_t)l * 1024 * 4096, ff2_b + l * 1024, tmp, tmp2,
        M, 1024, 2048, 4096, 4096);
    add_ln_kernel<<<M, 256, 0, stream>>>(h, tmp, tmp2, ln2_s + l * 1024, ln2_b + l * 1024, h_bf);
  }
  // ternary decoder: out = h @ w_eff^T + dec_b  (8-phase 256^2, padded M)
  gemm256_dec<<<dim3(MPAD / 256, 32000 / 256), 512, 131072, stream>>>(
      h_bf, weff, dec_b, out, M, 32000, 1024);
}

// Round 6
// 924.880 us; speedup vs baseline: 5.9571x; 1.0608x over previous
//
#include <hip/hip_runtime.h>
#include <hip/hip_bf16.h>
#include <math.h>

#define B_ 32
#define S_ 100
#define D_ 1024
#define H_ 16
#define L_ 2
#define V_ 32000
#define DF_ 4096
#define HD_ 64
#define MPAD 3328   // 3200 padded to 13*256

typedef __bf16 bf16x8 __attribute__((ext_vector_type(8)));
typedef float f32x4 __attribute__((ext_vector_type(4)));

__device__ __forceinline__ void async_copy16(const void* g, void* l) {
  __builtin_amdgcn_global_load_lds((const __attribute__((address_space(1))) void*)g,
                                   (__attribute__((address_space(3))) void*)l, 16, 0, 0);
}

// ------------------------------------------------------------------
// g = mean(|dec_w|) in float64 (order-insensitive to ~1e-13 relative)
// ------------------------------------------------------------------
__global__ void absmean_kernel(const float* __restrict__ w, double* __restrict__ out) {
  const long long n4 = (long long)V_ * D_ / 4;
  double s = 0.0;
  long long stride = (long long)gridDim.x * blockDim.x;
  for (long long i = (long long)blockIdx.x * blockDim.x + threadIdx.x; i < n4; i += stride) {
    float4 v = ((const float4*)w)[i];
    s += (double)fabsf(v.x) + (double)fabsf(v.y) + (double)fabsf(v.z) + (double)fabsf(v.w);
  }
#pragma unroll
  for (int off = 32; off > 0; off >>= 1) s += __shfl_down(s, off);
  __shared__ double sm[4];
  int lane = threadIdx.x & 63, wv = threadIdx.x >> 6;
  if (lane == 0) sm[wv] = s;
  __syncthreads();
  if (threadIdx.x == 0) atomicAdd(out, sm[0] + sm[1] + sm[2] + sm[3]);
}

// packed effective ternary weight as bf16: {q==0:+1, q==+1:-1, q==-1:0}
__global__ void quantize_kernel(const float* __restrict__ w, const double* __restrict__ gsum,
                                __hip_bfloat16* __restrict__ q) {
  const long long n4 = (long long)V_ * D_ / 4;
  double g = (*gsum) / ((double)V_ * D_) + 1e-6;
  long long stride = (long long)gridDim.x * blockDim.x;
  for (long long i = (long long)blockIdx.x * blockDim.x + threadIdx.x; i < n4; i += stride) {
    float4 v = ((const float4*)w)[i];
    union { __hip_bfloat16 h[4]; uint2 u; } o;
    float vv[4] = {v.x, v.y, v.z, v.w};
#pragma unroll
    for (int j = 0; j < 4; ++j) {
      double r = rint((double)vv[j] / g);  // half-to-even, matches np.round
      r = fmin(1.0, fmax(-1.0, r));
      float w_eff = (r == 0.0) ? 1.0f : ((r == 1.0) ? -1.0f : 0.0f);
      o.h[j] = __float2bfloat16(w_eff);  // exact
    }
    ((uint2*)q)[i] = o.u;
  }
}

// all four weight casts fused in one launch (fp32 -> bf16)
__global__ void cast_all_kernel(const float* __restrict__ qkv_w, const float* __restrict__ out_w,
                                const float* __restrict__ ff1_w, const float* __restrict__ ff2_w,
                                __hip_bfloat16* __restrict__ qd, __hip_bfloat16* __restrict__ od,
                                __hip_bfloat16* __restrict__ f1d, __hip_bfloat16* __restrict__ f2d) {
  const long long n1 = (long long)2 * 3072 * 1024 / 4;
  const long long n2 = n1 + (long long)2 * 1024 * 1024 / 4;
  const long long n3 = n2 + (long long)2 * 4096 * 1024 / 4;
  const long long n4 = n3 + (long long)2 * 1024 * 4096 / 4;
  long long stride = (long long)gridDim.x * blockDim.x;
  for (long long i = (long long)blockIdx.x * blockDim.x + threadIdx.x; i < n4; i += stride) {
    const float* src; __hip_bfloat16* dst; long long j;
    if (i < n1)      { src = qkv_w; dst = qd;  j = i; }
    else if (i < n2) { src = out_w; dst = od;  j = i - n1; }
    else if (i < n3) { src = ff1_w; dst = f1d; j = i - n2; }
    else             { src = ff2_w; dst = f2d; j = i - n3; }
    float4 v = ((const float4*)src)[j];
    union { __hip_bfloat16 h[4]; uint2 u; } o;
    o.h[0] = __float2bfloat16(v.x);
    o.h[1] = __float2bfloat16(v.y);
    o.h[2] = __float2bfloat16(v.z);
    o.h[3] = __float2bfloat16(v.w);
    ((uint2*)dst)[j] = o.u;
  }
}

// ------------------------------------------------------------------
// h[b,s,:] = emb[x[b,s],:] + pos[s,:]  -> fp32 h and bf16 h_bf
// ------------------------------------------------------------------
__global__ __launch_bounds__(256) void embed_kernel(const int* __restrict__ x,
    const float* __restrict__ emb, const float* __restrict__ pos,
    float* __restrict__ h, __hip_bfloat16* __restrict__ hb) {
  int row = blockIdx.x;  // b*S + s
  int s = row % S_;
  int tok = x[row];
  size_t eb = (size_t)tok * D_, pb = (size_t)s * D_, hb0 = (size_t)row * D_;
#pragma unroll
  for (int i = 0; i < 4; ++i) {
    int d = threadIdx.x + i * 256;
    float v = emb[eb + d] + pos[pb + d];
    h[hb0 + d] = v;
    hb[hb0 + d] = __float2bfloat16(v);
  }
}

__device__ __forceinline__ float gelu_exact(float v) {
  return 0.5f * v * (1.0f + erff(v * 0.70710678118654752f));
}

// ------------------------------------------------------------------
// m97-structure bf16 MFMA GEMM, 128x128 tile, BK=64 (double-pumped:
// two 32-col LDS halves per K-step, half the barrier pairs of BK=32).
// 4 waves (2x2 of 64x64). Split-K via blockIdx.z (z=0 -> C+bias,
// z=1 -> C2). XCD-bijective swizzle on (x,y).
// ------------------------------------------------------------------
template <int ACT, int OUTBF>
__global__ __launch_bounds__(256) void gemm_bf(const __hip_bfloat16* __restrict__ A,
    const __hip_bfloat16* __restrict__ Bm, const float* __restrict__ bias,
    void* __restrict__ C, void* __restrict__ C2, int M, int N, int K, int lda, int ldb) {
  __shared__ __bf16 As[128 * 64];  // [0..8191B] k0-31, [8192..16383B] k32-63
  __shared__ __bf16 Bs[128 * 64];
  int tid = threadIdx.x;
  int lane = tid & 63, wid = tid >> 6;
  int wr = wid >> 1, wc = wid & 1;  // wave -> 64x64 quadrant
  int z = blockIdx.z;

  // ---- bijective XCD swizzle (T1 / m204) ----
  int nwg = gridDim.x * gridDim.y;
  int orig = blockIdx.y * gridDim.x + blockIdx.x;
  int q = nwg >> 3, r = nwg & 7;
  int xcd = orig & 7, local = orig >> 3;
  int wgid = (xcd < r ? xcd * (q + 1) : r * (q + 1) + (xcd - r) * q) + local;
  int row0 = (wgid % gridDim.x) * 128;  // gridDim.x = M/128 (M fastest)
  int col0 = (wgid / gridDim.x) * 128;

  const __hip_bfloat16* Az = A + (size_t)z * K;
  const __hip_bfloat16* Bz = Bm + (size_t)z * K;
  int j0 = wid * 2;
  const __hip_bfloat16* Ag0 = Az + (size_t)(row0 + j0 * 16 + (lane >> 2)) * lda + (lane & 3) * 8;
  const __hip_bfloat16* Ag1 = Az + (size_t)(row0 + (j0 + 1) * 16 + (lane >> 2)) * lda + (lane & 3) * 8;
  const __hip_bfloat16* Bg0 = Bz + (size_t)(col0 + j0 * 16 + (lane >> 2)) * ldb + (lane & 3) * 8;
  const __hip_bfloat16* Bg1 = Bz + (size_t)(col0 + (j0 + 1) * 16 + (lane >> 2)) * ldb + (lane & 3) * 8;
  __bf16* Al0 = As + j0 * 512;
  __bf16* Al1 = As + (j0 + 1) * 512;
  __bf16* Bl0 = Bs + j0 * 512;
  __bf16* Bl1 = Bs + (j0 + 1) * 512;

  float bias_v[4];
#pragma unroll
  for (int ni = 0; ni < 4; ++ni)
    bias_v[ni] = (z == 0) ? bias[col0 + wc * 64 + ni * 16 + (lane & 15)] : 0.f;

  f32x4 acc[4][4];
#pragma unroll
  for (int mi = 0; mi < 4; ++mi)
#pragma unroll
    for (int ni = 0; ni < 4; ++ni) acc[mi][ni] = (f32x4){0.f, 0.f, 0.f, 0.f};

  const bf16x8* Asv = reinterpret_cast<const bf16x8*>(As);
  const bf16x8* Bsv = reinterpret_cast<const bf16x8*>(Bs);
  int afr = (wr * 64 + (lane & 15)) * 4 + (lane >> 4);  // in 8-elem units
  int bfr = (wc * 64 + (lane & 15)) * 4 + (lane >> 4);

  for (int k0 = 0; k0 < K; k0 += 64) {
    async_copy16(Ag0, Al0);  async_copy16(Ag0 + 32, (char*)Al0 + 8192);
    async_copy16(Ag1, Al1);  async_copy16(Ag1 + 32, (char*)Al1 + 8192);
    async_copy16(Bg0, Bl0);  async_copy16(Bg0 + 32, (char*)Bl0 + 8192);
    async_copy16(Bg1, Bl1);  async_copy16(Bg1 + 32, (char*)Bl1 + 8192);
    Ag0 += 64; Ag1 += 64; Bg0 += 64; Bg1 += 64;
    __syncthreads();  // drains vmcnt: LDS tile visible to all waves
    bf16x8 af[4][2], bq[4][2];
#pragma unroll
    for (int mi = 0; mi < 4; ++mi)
#pragma unroll
      for (int kk = 0; kk < 2; ++kk) af[mi][kk] = Asv[afr + mi * 64 + kk * 512];
#pragma unroll
    for (int ni = 0; ni < 4; ++ni)
#pragma unroll
      for (int kk = 0; kk < 2; ++kk) bq[ni][kk] = Bsv[bfr + ni * 64 + kk * 512];
#pragma unroll
    for (int mi = 0; mi < 4; ++mi)
#pragma unroll
      for (int ni = 0; ni < 4; ++ni)
#pragma unroll
        for (int kk = 0; kk < 2; ++kk)
          acc[mi][ni] = __builtin_amdgcn_mfma_f32_16x16x32_bf16(af[mi][kk], bq[ni][kk], acc[mi][ni], 0, 0, 0);
    __syncthreads();  // compute done before next-tile overwrite
  }

  float* Cf = (float*)((z == 0) ? C : C2);
  __hip_bfloat16* Cb = (__hip_bfloat16*)C;
#pragma unroll
  for (int mi = 0; mi < 4; ++mi) {
#pragma unroll
    for (int r2 = 0; r2 < 4; ++r2) {
      size_t m = row0 + wr * 64 + mi * 16 + (lane >> 4) * 4 + r2;
#pragma unroll
      for (int ni = 0; ni < 4; ++ni) {
        size_t n = col0 + wc * 64 + ni * 16 + (lane & 15);
        float v = acc[mi][ni][r2] + bias_v[ni];
        if (ACT == 1) v = gelu_exact(v);
        if (OUTBF) Cb[m * N + n] = __float2bfloat16(v);
        else       Cf[m * N + n] = v;
      }
    }
  }
}

// ------------------------------------------------------------------
// 8-phase 256x256 GEMM (T2+T3+T4+T5), BK=64, 512 threads = 8 waves
// (2M x 4N), per-wave 128x64 output. LDS 128 KiB. Raw s_barrier +
// counted vmcnt(4); XOR swizzle via pre-swizzled global source.
// (unchanged from R5 — proven correct, conflicts=0)
// ------------------------------------------------------------------
__global__ __launch_bounds__(512, 1) void gemm256_dec(
    const __hip_bfloat16* __restrict__ A, const __hip_bfloat16* __restrict__ Bm,
    const float* __restrict__ bias, float* __restrict__ C,
    int Mreal, int N, int K) {
  extern __shared__ char lds[];
  char* ldsA = lds;            // 65536 B
  char* ldsB = lds + 65536;    // 65536 B
  const int t = threadIdx.x;
  const int lane = t & 63, wid = t >> 6;
  const int wm = wid >> 2, wn = wid & 3;
  const int NT = K >> 6;

  // bijective XCD swizzle, M fastest
  int nwg = gridDim.x * gridDim.y;
  int orig = blockIdx.y * gridDim.x + blockIdx.x;
  int q = nwg >> 3, r = nwg & 7;
  int xcd = orig & 7, local = orig >> 3;
  int wgid = (xcd < r ? xcd * (q + 1) : r * (q + 1) + (xcd - r) * q) + local;
  int row0 = (wgid % gridDim.x) * 256;
  int col0 = (wgid / gridDim.x) * 256;

  const int rs = t >> 2;                                           // 0..127
  const int kc = ((((t & 3) << 4) ^ (((t >> 5) & 1) << 5)) >> 1);  // 0..31
  const __hip_bfloat16* Asrc = A + (size_t)(row0 + rs) * K + kc;
  const __hip_bfloat16* Bsrc = Bm + (size_t)(col0 + rs) * K + kc;

#define STAGE_A(b, h, tgt) do { \
    const __hip_bfloat16* _s = Asrc + (size_t)(h) * 128 * K + (tgt) * 64; \
    char* _d = ldsA + (b) * 32768 + (h) * 16384 + t * 16; \
    async_copy16(_s, _d); async_copy16(_s + 32, _d + 8192); } while (0)
#define STAGE_B(b, h, tgt) do { \
    const __hip_bfloat16* _s = Bsrc + (size_t)(h) * 128 * K + (tgt) * 64; \
    char* _d = ldsB + (b) * 32768 + (h) * 16384 + t * 16; \
    async_copy16(_s, _d); async_copy16(_s + 32, _d + 8192); } while (0)
#define SB() __builtin_amdgcn_sched_barrier(0)
#define BAR() __builtin_amdgcn_s_barrier()

  const int sb5 = ((lane >> 3) & 1) << 5;
  const int laneoff = ((lane & 15) << 6) + (((lane >> 4) << 4) ^ sb5);

  f32x4 acc[8][4];
#pragma unroll
  for (int i = 0; i < 8; ++i)
#pragma unroll
    for (int j = 0; j < 4; ++j) acc[i][j] = (f32x4){0.f, 0.f, 0.f, 0.f};

  STAGE_A(0, 0, 0); STAGE_B(0, 0, 0); STAGE_A(0, 1, 0); STAGE_B(0, 1, 0);
  STAGE_B(1, 0, 1); STAGE_A(1, 0, 1);
  asm volatile("s_waitcnt vmcnt(4)" ::: "memory");
  SB(); BAR(); SB();

  bf16x8 a[4][2], b[4][2];
  for (int T = 0; T < NT; ++T) {
    const int bs = T & 1;
    const char* Aw = ldsA + bs * 32768 + wm * 16384 + laneoff;
    const char* Bw = ldsB + bs * 32768 + (wn >> 1) * 16384 + (wn & 1) * 4096 + laneoff;
    // ---------- phase 0 ----------
#pragma unroll
    for (int mi = 0; mi < 4; ++mi)
#pragma unroll
      for (int kk = 0; kk < 2; ++kk)
        a[mi][kk] = *(const bf16x8*)(Aw + mi * 1024 + kk * 8192);
#pragma unroll
    for (int ni = 0; ni < 2; ++ni)
#pragma unroll
      for (int kk = 0; kk < 2; ++kk)
        b[ni][kk] = *(const bf16x8*)(Bw + ni * 1024 + kk * 8192);
    if (T + 1 < NT) STAGE_A(bs ^ 1, 1, T + 1);
    SB(); BAR(); SB();
    __builtin_amdgcn_s_setprio(1);
#pragma unroll
    for (int mi = 0; mi < 4; ++mi)
#pragma unroll
      for (int ni = 0; ni < 2; ++ni)
#pragma unroll
        for (int kk = 0; kk < 2; ++kk)
          acc[mi][ni] = __builtin_amdgcn_mfma_f32_16x16x32_bf16(a[mi][kk], b[ni][kk], acc[mi][ni], 0, 0, 0);
    __builtin_amdgcn_s_setprio(0);
    SB(); BAR(); SB();
    // ---------- phase 1 ----------
#pragma unroll
    for (int ni = 2; ni < 4; ++ni)
#pragma unroll
      for (int kk = 0; kk < 2; ++kk)
        b[ni][kk] = *(const bf16x8*)(Bw + ni * 1024 + kk * 8192);
    if (T + 1 < NT) STAGE_B(bs ^ 1, 1, T + 1);
    SB(); BAR(); SB();
    __builtin_amdgcn_s_setprio(1);
#pragma unroll
    for (int mi = 0; mi < 4; ++mi)
#pragma unroll
      for (int ni = 2; ni < 4; ++ni)
#pragma unroll
        for (int kk = 0; kk < 2; ++kk)
          acc[mi][ni] = __builtin_amdgcn_mfma_f32_16x16x32_bf16(a[mi][kk], b[ni][kk], acc[mi][ni], 0, 0, 0);
    __builtin_amdgcn_s_setprio(0);
    SB(); BAR(); SB();
    // ---------- phase 2 ----------
#pragma unroll
    for (int mi = 0; mi < 4; ++mi)
#pragma unroll
      for (int kk = 0; kk < 2; ++kk)
        a[mi][kk] = *(const bf16x8*)(Aw + (mi + 4) * 1024 + kk * 8192);
    if (T + 2 < NT) STAGE_B(bs, 0, T + 2);
    SB(); BAR(); SB();
    __builtin_amdgcn_s_setprio(1);
#pragma unroll
    for (int mi = 0; mi < 4; ++mi)
#pragma unroll
      for (int ni = 0; ni < 2; ++ni)
#pragma unroll
        for (int kk = 0; kk < 2; ++kk)
          acc[mi + 4][ni] = __builtin_amdgcn_mfma_f32_16x16x32_bf16(a[mi][kk], b[ni][kk], acc[mi + 4][ni], 0, 0, 0);
    __builtin_amdgcn_s_setprio(0);
    SB(); BAR(); SB();
    // ---------- phase 3 ----------
    if (T + 2 < NT) STAGE_A(bs, 0, T + 2);
    if (T < NT - 2) { asm volatile("s_waitcnt vmcnt(4)" ::: "memory"); }
    else            { asm volatile("s_waitcnt vmcnt(0)" ::: "memory"); }
    SB(); BAR(); SB();
    __builtin_amdgcn_s_setprio(1);
#pragma unroll
    for (int mi = 0; mi < 4; ++mi)
#pragma unroll
      for (int ni = 2; ni < 4; ++ni)
#pragma unroll
        for (int kk = 0; kk < 2; ++kk)
          acc[mi + 4][ni] = __builtin_amdgcn_mfma_f32_16x16x32_bf16(a[mi][kk], b[ni][kk], acc[mi + 4][ni], 0, 0, 0);
    __builtin_amdgcn_s_setprio(0);
    SB(); BAR(); SB();
  }
#undef STAGE_A
#undef STAGE_B
#undef SB
#undef BAR

  float bias_v[4];
#pragma unroll
  for (int ni = 0; ni < 4; ++ni)
    bias_v[ni] = bias[col0 + wn * 64 + ni * 16 + (lane & 15)];
#pragma unroll
  for (int mi = 0; mi < 8; ++mi) {
#pragma unroll
    for (int r2 = 0; r2 < 4; ++r2) {
      int m = row0 + wm * 128 + mi * 16 + (lane >> 4) * 4 + r2;
      if (m < Mreal) {
#pragma unroll
        for (int ni = 0; ni < 4; ++ni) {
          int n = col0 + wn * 64 + ni * 16 + (lane & 15);
          C[(size_t)m * N + n] = acc[mi][ni][r2] + bias_v[ni];
        }
      }
    }
  }
}

// ------------------------------------------------------------------
// Fused attention per (b,h): bf16 in/out, fp32 compute. S=100, hd=64.
// Sc padded to 101 (stride 100 = 8-way bank conflict; 101 coprime).
// ------------------------------------------------------------------
__global__ __launch_bounds__(128) void attn_kernel(const __hip_bfloat16* __restrict__ qkv,
                                                   __hip_bfloat16* __restrict__ ctx) {
  __shared__ float KV[50][64];
  __shared__ float Sc[100][101];
  int bh = blockIdx.x;  // b*H + h
  int b = bh >> 4, hh = bh & 15;
  int tid = threadIdx.x;
  size_t base = (size_t)b * S_ * (3 * D_);
  int hcol = hh * HD_;
  int r = tid;

  float qa[64];
  if (r < 100) {
    const __hip_bfloat16* qp = qkv + base + (size_t)r * (3 * D_) + hcol;
#pragma unroll
    for (int d0 = 0; d0 < 8; ++d0) {
      union { uint4 u; __hip_bfloat16 h[8]; } uu;
      uu.u = *(const uint4*)(qp + d0 * 8);
#pragma unroll
      for (int j = 0; j < 8; ++j) qa[d0 * 8 + j] = __bfloat162float(uu.h[j]);
    }
  }
  for (int tt = 0; tt < 2; ++tt) {
    __syncthreads();
    for (int idx = tid; idx < 400; idx += 128) {
      int j = idx >> 3, d8 = idx & 7;
      union { uint4 u; __hip_bfloat16 h[8]; } uu;
      uu.u = *(const uint4*)(qkv + base + (size_t)(tt * 50 + j) * (3 * D_) + D_ + hcol + d8 * 8);
#pragma unroll
      for (int e = 0; e < 8; ++e) KV[j][d8 * 8 + e] = __bfloat162float(uu.h[e]);
    }
    __syncthreads();
    if (r < 100) {
      for (int j = 0; j < 50; ++j) {
        float s = 0.f;
#pragma unroll
        for (int d0 = 0; d0 < 16; ++d0) {
          float4 kv = *(const float4*)&KV[j][d0 * 4];
          s += qa[d0 * 4 + 0] * kv.x + qa[d0 * 4 + 1] * kv.y +
               qa[d0 * 4 + 2] * kv.z + qa[d0 * 4 + 3] * kv.w;
        }
        Sc[r][tt * 50 + j] = s * 0.125f;
      }
    }
  }
  float inv_sum = 0.f;
  if (r < 100) {
    float mx = -1e30f;
    for (int j = 0; j < 100; ++j) mx = fmaxf(mx, Sc[r][j]);
    float sum = 0.f;
    for (int j = 0; j < 100; ++j) {
      float e = expf(Sc[r][j] - mx);
      Sc[r][j] = e;
      sum += e;
    }
    inv_sum = 1.0f / sum;
  }
  float ca[64];
#pragma unroll
  for (int d = 0; d < 64; ++d) ca[d] = 0.f;
  for (int tt = 0; tt < 2; ++tt) {
    __syncthreads();
    for (int idx = tid; idx < 400; idx += 128) {
      int j = idx >> 3, d8 = idx & 7;
      union { uint4 u; __hip_bfloat16 h[8]; } uu;
      uu.u = *(const uint4*)(qkv + base + (size_t)(tt * 50 + j) * (3 * D_) + 2 * D_ + hcol + d8 * 8);
#pragma unroll
      for (int e = 0; e < 8; ++e) KV[j][d8 * 8 + e] = __bfloat162float(uu.h[e]);
    }
    __syncthreads();
    if (r < 100) {
      for (int j = 0; j < 50; ++j) {
        float p = Sc[r][tt * 50 + j];
#pragma unroll
        for (int d0 = 0; d0 < 16; ++d0) {
          float4 kv = *(const float4*)&KV[j][d0 * 4];
          ca[d0 * 4 + 0] += p * kv.x;
          ca[d0 * 4 + 1] += p * kv.y;
          ca[d0 * 4 + 2] += p * kv.z;
          ca[d0 * 4 + 3] += p * kv.w;
        }
      }
    }
  }
  if (r < 100) {
    __hip_bfloat16* cp = ctx + ((size_t)b * S_ + r) * D_ + hcol;
#pragma unroll
    for (int d = 0; d < 64; ++d) cp[d] = __float2bfloat16(ca[d] * inv_sum);
  }
}

// ------------------------------------------------------------------
// h = LN(h + res [+ res2]) * scale + bias  (coalesced float4 per thread)
// ------------------------------------------------------------------
__device__ float block_sum_1024(float v) {
#pragma unroll
  for (int off = 32; off > 0; off >>= 1) v += __shfl_down(v, off);
  __shared__ float sm[4];
  __syncthreads();
  int lane = threadIdx.x & 63, wv = threadIdx.x >> 6;
  if (lane == 0) sm[wv] = v;
  __syncthreads();
  return sm[0] + sm[1] + sm[2] + sm[3];
}

__global__ __launch_bounds__(256) void add_ln_kernel(float* __restrict__ h,
    const float* __restrict__ res, const float* __restrict__ res2,
    const float* __restrict__ scale, const float* __restrict__ bias,
    __hip_bfloat16* __restrict__ hb) {
  size_t b4 = (size_t)blockIdx.x * 256 + threadIdx.x;  // float4 index within row-major stream
  float4 xa = ((const float4*)h)[b4];
  float4 xb = ((const float4*)res)[b4];
  float x[4] = {xa.x + xb.x, xa.y + xb.y, xa.z + xb.z, xa.w + xb.w};
  if (res2) {
    float4 xc = ((const float4*)res2)[b4];
    x[0] += xc.x; x[1] += xc.y; x[2] += xc.z; x[3] += xc.w;
  }
  float s = x[0] + x[1] + x[2] + x[3];
  float mu = block_sum_1024(s) * (1.0f / 1024.0f);
  float v = 0.f;
#pragma unroll
  for (int i = 0; i < 4; ++i) {
    float d = x[i] - mu;
    v += d * d;
  }
  float var = block_sum_1024(v) * (1.0f / 1024.0f);
  float rs = rsqrtf(var + 1e-5f);
  int d0 = threadIdx.x * 4;
  float4 sc = *(const float4*)&scale[d0];
  float4 bi = *(const float4*)&bias[d0];
  float o[4];
  o[0] = (x[0] - mu) * rs * sc.x + bi.x;
  o[1] = (x[1] - mu) * rs * sc.y + bi.y;
  o[2] = (x[2] - mu) * rs * sc.z + bi.z;
  o[3] = (x[3] - mu) * rs * sc.w + bi.w;
  ((float4*)h)[b4] = (float4){o[0], o[1], o[2], o[3]};
  union { __hip_bfloat16 hh[4]; uint2 u; } ob;
#pragma unroll
  for (int i = 0; i < 4; ++i) ob.hh[i] = __float2bfloat16(o[i]);
  ((uint2*)hb)[b4] = ob.u;
}

// ------------------------------------------------------------------
extern "C" void kernel_launch(void* const* d_in, const int* in_sizes, int n_in,
                              void* d_out, int out_size, void* d_ws, size_t ws_size,
                              hipStream_t stream) {
  const int* x       = (const int*)d_in[0];
  const float* emb   = (const float*)d_in[1];
  const float* pos   = (const float*)d_in[2];
  const float* qkv_w = (const float*)d_in[3];
  const float* qkv_b = (const float*)d_in[4];
  const float* out_w = (const float*)d_in[5];
  const float* out_b = (const float*)d_in[6];
  const float* ln1_s = (const float*)d_in[7];
  const float* ln1_b = (const float*)d_in[8];
  const float* ff1_w = (const float*)d_in[9];
  const float* ff1_b = (const float*)d_in[10];
  const float* ff2_w = (const float*)d_in[11];
  const float* ff2_b = (const float*)d_in[12];
  const float* ln2_s = (const float*)d_in[13];
  const float* ln2_b = (const float*)d_in[14];
  const float* dec_w = (const float*)d_in[15];
  const float* dec_b = (const float*)d_in[16];
  float* out = (float*)d_out;

  char* ws = (char*)d_ws;
  size_t off = 0;
  auto alloc = [&](size_t bytes) { void* p = ws + off; off += (bytes + 255) & ~(size_t)255; return p; };
  double* gsum            = (double*)alloc(256);
  float* h                = (float*)alloc((size_t)3200 * 1024 * 4);
  __hip_bfloat16* h_bf    = (__hip_bfloat16*)alloc((size_t)MPAD * 1024 * 2);  // padded for 256-tiles
  float* tmp              = (float*)alloc((size_t)3200 * 1024 * 4);
  float* tmp2             = (float*)alloc((size_t)3200 * 1024 * 4);
  __hip_bfloat16* ctx_bf  = (__hip_bfloat16*)alloc((size_t)3200 * 1024 * 2);
  __hip_bfloat16* big_bf  = (__hip_bfloat16*)alloc((size_t)3200 * 4096 * 2);  // qkv out / ff1 out
  __hip_bfloat16* weff    = (__hip_bfloat16*)alloc((size_t)32000 * 1024 * 2);
  __hip_bfloat16* qkvw_bf = (__hip_bfloat16*)alloc((size_t)2 * 3072 * 1024 * 2);
  __hip_bfloat16* outw_bf = (__hip_bfloat16*)alloc((size_t)2 * 1024 * 1024 * 2);
  __hip_bfloat16* ff1w_bf = (__hip_bfloat16*)alloc((size_t)2 * 4096 * 1024 * 2);
  __hip_bfloat16* ff2w_bf = (__hip_bfloat16*)alloc((size_t)2 * 1024 * 4096 * 2);

  hipMemsetAsync(gsum, 0, 256, stream);  // ws not re-poisoned between replays
  absmean_kernel<<<2048, 256, 0, stream>>>(dec_w, gsum);
  quantize_kernel<<<4096, 256, 0, stream>>>(dec_w, gsum, weff);
  cast_all_kernel<<<4096, 256, 0, stream>>>(qkv_w, out_w, ff1_w, ff2_w,
                                            qkvw_bf, outw_bf, ff1w_bf, ff2w_bf);
  embed_kernel<<<3200, 256, 0, stream>>>(x, emb, pos, h, h_bf);

  const int M = 3200;
  for (int l = 0; l < 2; ++l) {
    gemm_bf<0, 1><<<dim3(M / 128, 3072 / 128, 1), 256, 0, stream>>>(
        h_bf, qkvw_bf + (size_t)l * 3072 * 1024, qkv_b + l * 3072, big_bf, nullptr,
        M, 3072, 1024, 1024, 1024);
    attn_kernel<<<512, 128, 0, stream>>>(big_bf, ctx_bf);
    // out-proj: split-K2 (z=0 -> tmp + bias, z=1 -> tmp2)
    gemm_bf<0, 0><<<dim3(M / 128, 1024 / 128, 2), 256, 0, stream>>>(
        ctx_bf, outw_bf + (size_t)l * 1024 * 1024, out_b + l * 1024, tmp, tmp2,
        M, 1024, 512, 1024, 1024);
    add_ln_kernel<<<M, 256, 0, stream>>>(h, tmp, tmp2, ln1_s + l * 1024, ln1_b + l * 1024, h_bf);
    gemm_bf<1, 1><<<dim3(M / 128, 4096 / 128, 1), 256, 0, stream>>>(
        h_bf, ff1w_bf + (size_t)l * 4096 * 1024, ff1_b + l * 4096, big_bf, nullptr,
        M, 4096, 1024, 1024, 1024);
    // ff2: split-K2
    gemm_bf<0, 0><<<dim3(M / 128, 1024 / 128, 2), 256, 0, stream>>>(
        big_bf, ff2w_bf + (size_t)l * 1024 * 4096, ff2_b + l * 1024, tmp, tmp2,
        M, 1024, 2048, 4096, 4096);
    add_ln_kernel<<<M, 256, 0, stream>>>(h, tmp, tmp2, ln2_s + l * 1024, ln2_b + l * 1024, h_bf);
  }
  // ternary decoder: out = h @ w_eff^T + dec_b  (8-phase 256^2, padded M)
  gemm256_dec<<<dim3(MPAD / 256, 32000 / 256), 512, 131072, stream>>>(
      h_bf, weff, dec_b, out, M, 32000, 1024);
}